// Round 14
// baseline (451.420 us; speedup 1.0000x reference)
//
#include <hip/hip_runtime.h>
#include <hip/hip_bf16.h>

// Problem constants
constexpr int B = 4, N = 2048, M = 2048, H = 512, ITERS = 20;
constexpr float EPS_IN = 1e-5f;
constexpr float LOG2E = 1.4426950408889634f;
constexpr float LN2 = 0.6931471805599453f;

typedef unsigned short ushort_t;
typedef unsigned int uint_t;
typedef __attribute__((ext_vector_type(8))) short bf16x8;
typedef __attribute__((ext_vector_type(4))) float f32x4;

__device__ __forceinline__ float fexp2(float x) { return __builtin_amdgcn_exp2f(x); }
__device__ __forceinline__ float flog2(float x) { return __builtin_amdgcn_logf(x); }
__device__ __forceinline__ float blo(uint_t v) { return __uint_as_float(v << 16); }
__device__ __forceinline__ float bhi(uint_t v) { return __uint_as_float(v & 0xffff0000u); }
// round-to-nearest-even f32 -> bf16 (inputs finite)
__device__ __forceinline__ uint_t bf16rn(float f) {
  uint_t x = __float_as_uint(f);
  return (x + 0x7fffu + ((x >> 16) & 1u)) >> 16;
}

// ---------------------------------------------------------------------------
// Kernel 0: Wq f32 [64][512] -> bf16 wqh (row-major, L2-resident for proj).
// ---------------------------------------------------------------------------
__global__ __launch_bounds__(256) void wqconv_kernel(
    const float* __restrict__ Wq, ushort_t* __restrict__ wqh) {
  int g = blockIdx.x * 256 + threadIdx.x;  // 0..8191, 4 elems each
  float4 v = *(const float4*)(Wq + (size_t)g * 4);
  uint2 pk;
  pk.x = bf16rn(v.x) | (bf16rn(v.y) << 16);
  pk.y = bf16rn(v.z) | (bf16rn(v.w) << 16);
  *(uint2*)(wqh + (size_t)g * 4) = pk;
}

// ---------------------------------------------------------------------------
// Kernel 1 (MFMA): projections -> qwh[row][k] (16384 x 64 bf16) + f32 norms.
// 256 blocks x 4 waves; each wave = 16 rows x 64 cols, K=512 in 16 steps of
// mfma_f32_16x16x32_bf16.  A-frag cvt'd from f32 x/y on the fly; B-frag read
// from bf16 wqh (L2-hot).  No LDS.  C/D layout col=lane&15,row=(lane>>4)*4+reg
// (HW-verified m89/m91; same A/B addressing as the proven dist kernel).
// ---------------------------------------------------------------------------
__global__ __launch_bounds__(256) void proj_kernel(
    const float* __restrict__ x, const float* __restrict__ y,
    const ushort_t* __restrict__ wqh, const float* __restrict__ bq,
    ushort_t* __restrict__ qwh, float* __restrict__ norms,
    float* __restrict__ stats) {
  int t = threadIdx.x;
  if (blockIdx.x == 0 && t < 32) stats[t] = 0.0f;
  int w = t >> 6, lane = t & 63;
  int fr = lane & 15, fh = (lane >> 4) * 8;
  int rw = blockIdx.x * 64 + w * 16;  // wave row base (16 rows, same tensor)
  int row = rw + fr;
  const float* src = (row < B * N) ? x + (size_t)row * H
                                   : y + (size_t)(row - B * N) * H;

  f32x4 acc[4];
#pragma unroll
  for (int j = 0; j < 4; j++) acc[j] = (f32x4){0.f, 0.f, 0.f, 0.f};

#pragma unroll
  for (int ks = 0; ks < 16; ks++) {
    float4 a0 = *(const float4*)(src + ks * 32 + fh);
    float4 a1 = *(const float4*)(src + ks * 32 + fh + 4);
    union { uint4 u; bf16x8 h; } ac;
    ac.u.x = bf16rn(a0.x) | (bf16rn(a0.y) << 16);
    ac.u.y = bf16rn(a0.z) | (bf16rn(a0.w) << 16);
    ac.u.z = bf16rn(a1.x) | (bf16rn(a1.y) << 16);
    ac.u.w = bf16rn(a1.z) | (bf16rn(a1.w) << 16);
    bf16x8 aF = ac.h;
#pragma unroll
    for (int j = 0; j < 4; j++) {
      bf16x8 bF = *(const bf16x8*)(wqh + (size_t)(j * 16 + fr) * H + ks * 32 + fh);
      acc[j] = __builtin_amdgcn_mfma_f32_16x16x32_bf16(aF, bF, acc[j], 0, 0, 0);
    }
  }

  float bqv[4];
#pragma unroll
  for (int j = 0; j < 4; j++) bqv[j] = bq[j * 16 + fr];

#pragma unroll
  for (int reg = 0; reg < 4; reg++) {
    int r = rw + ((lane >> 4) << 2) + reg;
    float nr = 0.0f;
#pragma unroll
    for (int j = 0; j < 4; j++) {
      float vv = acc[j][reg] + bqv[j];
      qwh[(size_t)r * 64 + j * 16 + fr] = (ushort_t)bf16rn(vv);
      nr = fmaf(vv, vv, nr);
    }
    nr += __shfl_xor(nr, 1, 64);
    nr += __shfl_xor(nr, 2, 64);
    nr += __shfl_xor(nr, 4, 64);
    nr += __shfl_xor(nr, 8, 64);
    if (fr == 0) norms[r] = nr;
  }
}

// ---------------------------------------------------------------------------
// Kernel 2 (MFMA): e[b,n,m] = exp(-dist) -> bf16 in d_out + per-batch stats.
// (round-13-proven)
// ---------------------------------------------------------------------------
__global__ __launch_bounds__(256) void dist_kernel(
    const ushort_t* __restrict__ qwh, const float* __restrict__ norms,
    ushort_t* __restrict__ e, float* __restrict__ stats) {
  __shared__ __align__(16) ushort_t eT[128 * 136];  // 34 KB
  __shared__ float xnL[128], ynL[128], scr[12];
  int t = threadIdx.x;
  int b = blockIdx.z;
  int n0 = blockIdx.x * 128, m0 = blockIdx.y * 128;
  int w = t >> 6, lane = t & 63;

  if (t < 128) xnL[t] = norms[b * N + n0 + t];
  else ynL[t - 128] = norms[B * N + b * M + m0 + (t - 128)];

  int wr = (w >> 1) * 64, wc = (w & 1) * 64;
  int fr = lane & 15, fk = (lane >> 4) * 8;

  f32x4 acc[4][4];
#pragma unroll
  for (int i = 0; i < 4; i++)
#pragma unroll
    for (int j = 0; j < 4; j++) acc[i][j] = (f32x4){0.f, 0.f, 0.f, 0.f};

  const ushort_t* xb = qwh + (size_t)(b * N + n0 + wr + fr) * 64 + fk;
  const ushort_t* yb = qwh + (size_t)(B * N + b * M + m0 + wc + fr) * 64 + fk;
#pragma unroll
  for (int kg = 0; kg < 2; kg++) {
    bf16x8 aF[4], bF[4];
#pragma unroll
    for (int i = 0; i < 4; i++) {
      aF[i] = *(const bf16x8*)(xb + (size_t)i * 16 * 64 + kg * 32);
      bF[i] = *(const bf16x8*)(yb + (size_t)i * 16 * 64 + kg * 32);
    }
#pragma unroll
    for (int i = 0; i < 4; i++)
#pragma unroll
      for (int j = 0; j < 4; j++)
        acc[i][j] = __builtin_amdgcn_mfma_f32_16x16x32_bf16(
            aF[i], bF[j], acc[i][j], 0, 0, 0);
  }
  __syncthreads();

  float lsum = 0.0f, lsq = 0.0f, lmax = 0.0f;
#pragma unroll
  for (int i = 0; i < 4; i++) {
    int rl = wr + i * 16 + ((lane >> 4) << 2);
    float xn0 = xnL[rl], xn1 = xnL[rl + 1], xn2 = xnL[rl + 2], xn3 = xnL[rl + 3];
#pragma unroll
    for (int j = 0; j < 4; j++) {
      int cl = wc + j * 16 + (lane & 15);
      float yn_ = ynL[cl];
      float v0 = __expf(-(xn0 + yn_ - 2.0f * acc[i][j][0]));
      float v1 = __expf(-(xn1 + yn_ - 2.0f * acc[i][j][1]));
      float v2 = __expf(-(xn2 + yn_ - 2.0f * acc[i][j][2]));
      float v3 = __expf(-(xn3 + yn_ - 2.0f * acc[i][j][3]));
      lsum += (v0 + v1) + (v2 + v3);
      lsq += (v0 * v0 + v1 * v1) + (v2 * v2 + v3 * v3);
      lmax = fmaxf(fmaxf(lmax, fmaxf(v0, v1)), fmaxf(v2, v3));
      eT[(rl + 0) * 136 + cl] = (ushort_t)bf16rn(v0);
      eT[(rl + 1) * 136 + cl] = (ushort_t)bf16rn(v1);
      eT[(rl + 2) * 136 + cl] = (ushort_t)bf16rn(v2);
      eT[(rl + 3) * 136 + cl] = (ushort_t)bf16rn(v3);
    }
  }
#pragma unroll
  for (int off = 32; off; off >>= 1) {
    lsum += __shfl_xor(lsum, off, 64);
    lsq += __shfl_xor(lsq, off, 64);
    lmax = fmaxf(lmax, __shfl_xor(lmax, off, 64));
  }
  if (lane == 0) { scr[w] = lsum; scr[4 + w] = lsq; scr[8 + w] = lmax; }
  __syncthreads();

#pragma unroll
  for (int p = 0; p < 8; p++) {
    int row = p * 16 + (t >> 4);
    int cs = (t & 15) * 8;
    uint4 vv = *(const uint4*)&eT[row * 136 + cs];
    *(uint4*)(e + (size_t)(b * N + n0 + row) * M + m0 + cs) = vv;
  }
  if (t == 0) {
    float ssum = scr[0] + scr[1] + scr[2] + scr[3];
    float ssq = scr[4] + scr[5] + scr[6] + scr[7];
    float smax = fmaxf(fmaxf(scr[8], scr[9]), fmaxf(scr[10], scr[11]));
    atomicAdd(&stats[b * 4 + 0], ssum);
    atomicAdd(&stats[b * 4 + 1], ssq);
    atomicMax((unsigned int*)&stats[b * 4 + 2], __float_as_uint(smax));
  }
}

// ---------------------------------------------------------------------------
// Kernel 3: per-batch params + zero the three colsum rotation buffers.
// ---------------------------------------------------------------------------
__global__ void params_csinit_kernel(const float* __restrict__ stats,
                                     const float* __restrict__ in_w,
                                     const float* __restrict__ in_b,
                                     float* __restrict__ params,
                                     float* __restrict__ csb) {
  int g = blockIdx.x * 256 + threadIdx.x;
  *(float4*)(csb + g * 4) = float4{0.f, 0.f, 0.f, 0.f};
  if (blockIdx.x == 0 && threadIdx.x < B) {
    int b = threadIdx.x;
    float NMf = (float)N * (float)M;
    float mean = stats[b * 4 + 0] / NMf;
    float var = stats[b * 4 + 1] / NMf - mean * mean;
    var = fmaxf(var, 0.0f);
    float stdv = sqrtf(var + EPS_IN);
    float s = in_w[0] / stdv;
    float t = in_b[0] - mean * s;
    float emax = __uint_as_float(((const unsigned int*)stats)[b * 4 + 2]);
    float Amax = fmaxf(fmaf(s, emax, t), t);
    float KK = fmaxf(Amax - 60.0f, 0.0f);
    params[b * 8 + 0] = s * LOG2E;
    params[b * 8 + 1] = (t - 2.0f * KK) * LOG2E;
    params[b * 8 + 2] = KK;
    params[b * 8 + 3] = __expf(-KK);
    params[b * 8 + 4] = __expf(KK);
  }
}

// ---------------------------------------------------------------------------
// Kernel 5: fused sinkhorn iteration (round-9 core).  NEW: rotated-quarter
// parallel combine into plain-indexed colacc (4 rounds, all waves active,
// 14 b128/wave vs 64 serialized); Ds recomputed from L2-hot cs_cur in the
// epilogue (no Ds LDS).  LDS 16 KB.
// ---------------------------------------------------------------------------
#define PASS1(uu, off, PA, PB)                           \
  {                                                      \
    float4 ca = *(const float4*)&C2a[(off) + ln4];       \
    float4 cb = *(const float4*)&C2b[(off) + ln4];       \
    PA.x = fexp2(fmaf(blo(uu.x), sL, ca.x));             \
    PA.y = fexp2(fmaf(bhi(uu.x), sL, ca.y));             \
    PA.z = fexp2(fmaf(blo(uu.y), sL, ca.z));             \
    PA.w = fexp2(fmaf(bhi(uu.y), sL, ca.w));             \
    PB.x = fexp2(fmaf(blo(uu.z), sL, cb.x));             \
    PB.y = fexp2(fmaf(bhi(uu.z), sL, cb.y));             \
    PB.z = fexp2(fmaf(blo(uu.w), sL, cb.z));             \
    PB.w = fexp2(fmaf(bhi(uu.w), sL, cb.w));             \
    s0 += PA.x + PB.x;                                   \
    s1 += PA.y + PB.y;                                   \
    s2 += PA.z + PB.z;                                   \
    s3 += PA.w + PB.w;                                   \
  }

#define PASS2(PA, PB, AA, BB)                            \
  {                                                      \
    AA.x = fmaf(PA.x, g, AA.x);                          \
    AA.y = fmaf(PA.y, g, AA.y);                          \
    AA.z = fmaf(PA.z, g, AA.z);                          \
    AA.w = fmaf(PA.w, g, AA.w);                          \
    BB.x = fmaf(PB.x, g, BB.x);                          \
    BB.y = fmaf(PB.y, g, BB.y);                          \
    BB.z = fmaf(PB.z, g, BB.z);                          \
    BB.w = fmaf(PB.w, g, BB.w);                          \
  }

__global__ __launch_bounds__(256) void sink_pass(
    const ushort_t* __restrict__ e, const float* __restrict__ params,
    const float* __restrict__ cs_cur, float* __restrict__ cs_nxt,
    float* __restrict__ cs_zz, float* __restrict__ R) {
  __shared__ __align__(16) float C2a[1024], C2b[1024];
  __shared__ __align__(16) float colacc[2048];
  int t = threadIdx.x;
  int b = blockIdx.y, blk = blockIdx.x;  // blk 0..255
  int w = t >> 6, lane = t & 63;
  int ln4 = lane * 4;
  const float* pr = params + b * 8;
  float sL = pr[0], c0L = pr[1], KK = pr[2], enk = pr[3], ekk = pr[4];

  // issue both rows' e-loads FIRST: latency hides under the prologue
  int r0 = blk * 8 + w * 2;
  const ushort_t* ep = e + (size_t)(b * N + r0) * M + lane * 8;
  uint4 u0 = *(const uint4*)(ep);
  uint4 u1 = *(const uint4*)(ep + 512);
  uint4 u2 = *(const uint4*)(ep + 1024);
  uint4 u3 = *(const uint4*)(ep + 1536);
  const ushort_t* ep2 = ep + M;
  uint4 v0 = *(const uint4*)(ep2);
  uint4 v1 = *(const uint4*)(ep2 + 512);
  uint4 v2 = *(const uint4*)(ep2 + 1024);
  uint4 v3 = *(const uint4*)(ep2 + 1536);

  if (blk == 0) {  // coalesced zero of next iteration's accumulator
#pragma unroll
    for (int k = 0; k < 2; k++)
      *(float4*)(cs_zz + b * M + (k * 256 + t) * 4) = float4{0.f, 0.f, 0.f, 0.f};
  }
  {  // prologue: thread t owns columns [t*8, t*8+8)
    float4 c0 = *(const float4*)(cs_cur + b * M + t * 8);
    float4 c1 = *(const float4*)(cs_cur + b * M + t * 8 + 4);
    c0.x += enk; c0.y += enk; c0.z += enk; c0.w += enk;
    c1.x += enk; c1.y += enk; c1.z += enk; c1.w += enk;
    float4 ca, cb;
    ca.x = c0L - flog2(c0.x); ca.y = c0L - flog2(c0.y);
    ca.z = c0L - flog2(c0.z); ca.w = c0L - flog2(c0.w);
    cb.x = c0L - flog2(c1.x); cb.y = c0L - flog2(c1.y);
    cb.z = c0L - flog2(c1.z); cb.w = c0L - flog2(c1.w);
    *(float4*)&C2a[w * 256 + ln4] = ca;
    *(float4*)&C2b[w * 256 + ln4] = cb;
  }
  __syncthreads();

  float4 accA0 = {0,0,0,0}, accA1 = {0,0,0,0}, accA2 = {0,0,0,0}, accA3 = {0,0,0,0};
  float4 accB0 = {0,0,0,0}, accB1 = {0,0,0,0}, accB2 = {0,0,0,0}, accB3 = {0,0,0,0};
  float4 pA0, pA1, pA2, pA3, pB0, pB1, pB2, pB3;

  // ---- row 0 ----
  {
    float s0 = 0, s1 = 0, s2 = 0, s3 = 0;
    PASS1(u0, 0, pA0, pB0)
    PASS1(u1, 256, pA1, pB1)
    PASS1(u2, 512, pA2, pB2)
    PASS1(u3, 768, pA3, pB3)
    float sum = (s0 + s1) + (s2 + s3);
#pragma unroll
    for (int off = 32; off; off >>= 1) sum += __shfl_xor(sum, off, 64);
    float sumtot = sum + enk;
    float ls = flog2(sumtot);
    if (lane == 0) R[b * N + r0] = KK + LN2 * ls;
    float g = fexp2(-KK * LOG2E - ls);  // g = enk/sumtot
    PASS2(pA0, pB0, accA0, accB0)
    PASS2(pA1, pB1, accA1, accB1)
    PASS2(pA2, pB2, accA2, accB2)
    PASS2(pA3, pB3, accA3, accB3)
  }
  // ---- row 1 ----
  {
    float s0 = 0, s1 = 0, s2 = 0, s3 = 0;
    PASS1(v0, 0, pA0, pB0)
    PASS1(v1, 256, pA1, pB1)
    PASS1(v2, 512, pA2, pB2)
    PASS1(v3, 768, pA3, pB3)
    float sum = (s0 + s1) + (s2 + s3);
#pragma unroll
    for (int off = 32; off; off >>= 1) sum += __shfl_xor(sum, off, 64);
    float sumtot = sum + enk;
    float ls = flog2(sumtot);
    if (lane == 0) R[b * N + r0 + 1] = KK + LN2 * ls;
    float g = fexp2(-KK * LOG2E - ls);
    PASS2(pA0, pB0, accA0, accB0)
    PASS2(pA1, pB1, accA1, accB1)
    PASS2(pA2, pB2, accA2, accB2)
    PASS2(pA3, pB3, accA3, accB3)
  }

  // rotated-quarter combine: round r, wave w handles quarter q=(w+r)&3.
  // accA_it/accB_it hold cols it*512 + lane*8 + {0..3}/{4..7} -> plain index.
#pragma unroll
  for (int r = 0; r < 4; r++) {
    int q = (w + r) & 3;
    float* qb = &colacc[q * 512 + lane * 8];
    float4 va, vb;
    switch (q) {
      case 0: va = accA0; vb = accB0; break;
      case 1: va = accA1; vb = accB1; break;
      case 2: va = accA2; vb = accB2; break;
      default: va = accA3; vb = accB3; break;
    }
    if (r == 0) {
      *(float4*)qb = va;
      *(float4*)(qb + 4) = vb;
    } else {
      float4 o0 = *(float4*)qb, o1 = *(float4*)(qb + 4);
      o0.x += va.x; o0.y += va.y; o0.z += va.z; o0.w += va.w;
      o1.x += vb.x; o1.y += vb.y; o1.z += vb.z; o1.w += vb.w;
      *(float4*)qb = o0;
      *(float4*)(qb + 4) = o1;
    }
    __syncthreads();
  }

  {  // epilogue: WAVE-COALESCED atomics; thread t owns columns {k*256+t}.
     // Ds recomputed from L2-hot cs_cur (no LDS).
#pragma unroll
    for (int k = 0; k < 8; k++) {
      int j = k * 256 + t;
      float v = cs_cur[b * M + j] + enk;
      atomicAdd(&cs_nxt[b * M + j], colacc[j] * (ekk * v));
    }
  }
}

// ---------------------------------------------------------------------------
// Kernel 7: aw[i] = exp2(max_j fma(e,sL,C2L_j) + (KK - R_i)*log2e).
// ---------------------------------------------------------------------------
__global__ __launch_bounds__(256) void awmax_kernel(
    const ushort_t* __restrict__ e, const float* __restrict__ params,
    const float* __restrict__ cs_fin, const float* __restrict__ R,
    float* __restrict__ aw) {
  __shared__ __align__(16) float C2a[1024], C2b[1024];
  int t = threadIdx.x;
  int b = blockIdx.y, blk = blockIdx.x;
  const float* pr = params + b * 8;
  float sL = pr[0], c0L = pr[1], KK = pr[2], enk = pr[3];
  {
    float4 v0 = *(const float4*)(cs_fin + b * M + t * 8);
    float4 v1 = *(const float4*)(cs_fin + b * M + t * 8 + 4);
    float4 ca, cb;
    ca.x = c0L - flog2(v0.x + enk); ca.y = c0L - flog2(v0.y + enk);
    ca.z = c0L - flog2(v0.z + enk); ca.w = c0L - flog2(v0.w + enk);
    cb.x = c0L - flog2(v1.x + enk); cb.y = c0L - flog2(v1.y + enk);
    cb.z = c0L - flog2(v1.z + enk); cb.w = c0L - flog2(v1.w + enk);
    int it = t >> 6, ln = t & 63;
    *(float4*)&C2a[it * 256 + ln * 4] = ca;
    *(float4*)&C2b[it * 256 + ln * 4] = cb;
  }
  __syncthreads();

  int w = t >> 6, lane = t & 63;
  int ln4 = lane * 4;
  int r0 = blk * 16 + w * 4;
  const ushort_t* erow = e + (size_t)(b * N + r0) * M;
#pragma unroll
  for (int rr = 0; rr < 4; rr++) {
    float mx = -3.4e38f;
#pragma unroll
    for (int it = 0; it < 4; it++) {
      uint4 u = *(const uint4*)(erow + (size_t)rr * M + it * 512 + lane * 8);
      float4 ca = *(const float4*)&C2a[it * 256 + ln4];
      float4 cb = *(const float4*)&C2b[it * 256 + ln4];
      mx = fmaxf(mx, fmaf(blo(u.x), sL, ca.x));
      mx = fmaxf(mx, fmaf(bhi(u.x), sL, ca.y));
      mx = fmaxf(mx, fmaf(blo(u.y), sL, ca.z));
      mx = fmaxf(mx, fmaf(bhi(u.y), sL, ca.w));
      mx = fmaxf(mx, fmaf(blo(u.z), sL, cb.x));
      mx = fmaxf(mx, fmaf(bhi(u.z), sL, cb.y));
      mx = fmaxf(mx, fmaf(blo(u.w), sL, cb.z));
      mx = fmaxf(mx, fmaf(bhi(u.w), sL, cb.w));
    }
#pragma unroll
    for (int off = 32; off; off >>= 1) mx = fmaxf(mx, __shfl_xor(mx, off, 64));
    if (lane == 0) {
      float Rr = R[b * N + r0 + rr];
      aw[b * N + r0 + rr] = fexp2(mx + (KK - Rr) * LOG2E);
    }
  }
}

// ---------------------------------------------------------------------------
// Kernel 8: out[b,n,m] = aw[b,n] * aw[b,m], float4 stores.
// ---------------------------------------------------------------------------
__global__ __launch_bounds__(256) void outer_kernel(const float* __restrict__ aw,
                                                    float* __restrict__ out) {
  size_t idx = (size_t)blockIdx.x * 256 + threadIdx.x;
  int b = (int)(idx >> 20);
  size_t rem = idx & ((1u << 20) - 1);
  int n = (int)(rem >> 9);
  int m4 = (int)(rem & 511) << 2;
  float a = aw[b * N + n];
  float4 wv = *(const float4*)(aw + b * N + m4);
  float4 o = {a * wv.x, a * wv.y, a * wv.z, a * wv.w};
  *(float4*)(out + (idx << 2)) = o;
}

// ---------------------------------------------------------------------------
extern "C" void kernel_launch(void* const* d_in, const int* in_sizes, int n_in,
                              void* d_out, int out_size, void* d_ws, size_t ws_size,
                              hipStream_t stream) {
  const float* x = (const float*)d_in[0];
  const float* y = (const float*)d_in[1];
  const float* Wq = (const float*)d_in[2];
  const float* bq = (const float*)d_in[3];
  const float* in_w = (const float*)d_in[4];
  const float* in_b = (const float*)d_in[5];
  ushort_t* e = (ushort_t*)d_out;  // 33.5 MB bf16 scratch; overwritten by outer

  float* ws = (float*)d_ws;
  ushort_t* qwh = (ushort_t*)ws;     // 16384*64 bf16 (occupies 524288 f32)
  float* norms = ws + 1048576;       // 16384
  float* R = norms + 16384;          // 8192
  float* csb0 = R + 8192;            // 8192
  float* csb1 = csb0 + 8192;         // 8192
  float* csb2 = csb1 + 8192;         // 8192
  float* aw = csb2 + 8192;           // 8192
  float* stats = aw + 8192;          // 32
  float* params = stats + 32;        // 32
  ushort_t* wqh = (ushort_t*)(params + 32);  // 64*512 bf16
  float* csb[3] = {csb0, csb1, csb2};

  wqconv_kernel<<<32, 256, 0, stream>>>(Wq, wqh);
  proj_kernel<<<256, 256, 0, stream>>>(x, y, wqh, bq, qwh, norms, stats);
  dist_kernel<<<dim3(16, 16, B), 256, 0, stream>>>(qwh, norms, e, stats);
  params_csinit_kernel<<<24, 256, 0, stream>>>(stats, in_w, in_b, params, csb0);

  for (int it = 0; it < ITERS; it++) {
    sink_pass<<<dim3(256, B), 256, 0, stream>>>(
        e, params, csb[it % 3], csb[(it + 1) % 3], csb[(it + 2) % 3], R);
  }
  awmax_kernel<<<dim3(128, B), 256, 0, stream>>>(e, params, csb[ITERS % 3], R, aw);
  outer_kernel<<<16384, 256, 0, stream>>>(aw, (float*)d_out);
}

// Round 15
// 426.416 us; speedup vs baseline: 1.0586x; 1.0586x over previous
//
#include <hip/hip_runtime.h>
#include <hip/hip_bf16.h>

// Problem constants
constexpr int B = 4, N = 2048, M = 2048, H = 512, ITERS = 20;
constexpr float EPS_IN = 1e-5f;
constexpr float LOG2E = 1.4426950408889634f;
constexpr float LN2 = 0.6931471805599453f;

typedef unsigned short ushort_t;
typedef unsigned int uint_t;
typedef __attribute__((ext_vector_type(8))) short bf16x8;
typedef __attribute__((ext_vector_type(4))) float f32x4;

__device__ __forceinline__ float fexp2(float x) { return __builtin_amdgcn_exp2f(x); }
__device__ __forceinline__ float flog2(float x) { return __builtin_amdgcn_logf(x); }
__device__ __forceinline__ float blo(uint_t v) { return __uint_as_float(v << 16); }
__device__ __forceinline__ float bhi(uint_t v) { return __uint_as_float(v & 0xffff0000u); }
// round-to-nearest-even f32 -> bf16 (inputs finite)
__device__ __forceinline__ uint_t bf16rn(float f) {
  uint_t x = __float_as_uint(f);
  return (x + 0x7fffu + ((x >> 16) & 1u)) >> 16;
}

// ---------------------------------------------------------------------------
// Kernel 0: Wq f32 [64][512] -> bf16 wqh (row-major, L2-resident for proj).
// ---------------------------------------------------------------------------
__global__ __launch_bounds__(256) void wqconv_kernel(
    const float* __restrict__ Wq, ushort_t* __restrict__ wqh) {
  int g = blockIdx.x * 256 + threadIdx.x;  // 0..8191, 4 elems each
  float4 v = *(const float4*)(Wq + (size_t)g * 4);
  uint2 pk;
  pk.x = bf16rn(v.x) | (bf16rn(v.y) << 16);
  pk.y = bf16rn(v.z) | (bf16rn(v.w) << 16);
  *(uint2*)(wqh + (size_t)g * 4) = pk;
}

// ---------------------------------------------------------------------------
// Kernel 1 (MFMA): projections -> qwh[row][k] (16384 x 64 bf16) + f32 norms.
// (round-14-proven)
// ---------------------------------------------------------------------------
__global__ __launch_bounds__(256) void proj_kernel(
    const float* __restrict__ x, const float* __restrict__ y,
    const ushort_t* __restrict__ wqh, const float* __restrict__ bq,
    ushort_t* __restrict__ qwh, float* __restrict__ norms,
    float* __restrict__ stats) {
  int t = threadIdx.x;
  if (blockIdx.x == 0 && t < 32) stats[t] = 0.0f;
  int w = t >> 6, lane = t & 63;
  int fr = lane & 15, fh = (lane >> 4) * 8;
  int rw = blockIdx.x * 64 + w * 16;
  int row = rw + fr;
  const float* src = (row < B * N) ? x + (size_t)row * H
                                   : y + (size_t)(row - B * N) * H;

  f32x4 acc[4];
#pragma unroll
  for (int j = 0; j < 4; j++) acc[j] = (f32x4){0.f, 0.f, 0.f, 0.f};

#pragma unroll
  for (int ks = 0; ks < 16; ks++) {
    float4 a0 = *(const float4*)(src + ks * 32 + fh);
    float4 a1 = *(const float4*)(src + ks * 32 + fh + 4);
    union { uint4 u; bf16x8 h; } ac;
    ac.u.x = bf16rn(a0.x) | (bf16rn(a0.y) << 16);
    ac.u.y = bf16rn(a0.z) | (bf16rn(a0.w) << 16);
    ac.u.z = bf16rn(a1.x) | (bf16rn(a1.y) << 16);
    ac.u.w = bf16rn(a1.z) | (bf16rn(a1.w) << 16);
    bf16x8 aF = ac.h;
#pragma unroll
    for (int j = 0; j < 4; j++) {
      bf16x8 bF = *(const bf16x8*)(wqh + (size_t)(j * 16 + fr) * H + ks * 32 + fh);
      acc[j] = __builtin_amdgcn_mfma_f32_16x16x32_bf16(aF, bF, acc[j], 0, 0, 0);
    }
  }

  float bqv[4];
#pragma unroll
  for (int j = 0; j < 4; j++) bqv[j] = bq[j * 16 + fr];

#pragma unroll
  for (int reg = 0; reg < 4; reg++) {
    int r = rw + ((lane >> 4) << 2) + reg;
    float nr = 0.0f;
#pragma unroll
    for (int j = 0; j < 4; j++) {
      float vv = acc[j][reg] + bqv[j];
      qwh[(size_t)r * 64 + j * 16 + fr] = (ushort_t)bf16rn(vv);
      nr = fmaf(vv, vv, nr);
    }
    nr += __shfl_xor(nr, 1, 64);
    nr += __shfl_xor(nr, 2, 64);
    nr += __shfl_xor(nr, 4, 64);
    nr += __shfl_xor(nr, 8, 64);
    if (fr == 0) norms[r] = nr;
  }
}

// ---------------------------------------------------------------------------
// Kernel 2 (MFMA): e[b,n,m] = exp(-dist) -> bf16 in d_out + per-batch stats.
// NEW: 64x128 tile, 2048 blocks (8 blocks/CU, LDS ~18 KB) for latency hiding.
// Wave sub-tile 32x64: acc[2][4], 16 MFMA.  Same verified frag/C-layout.
// ---------------------------------------------------------------------------
__global__ __launch_bounds__(256) void dist_kernel(
    const ushort_t* __restrict__ qwh, const float* __restrict__ norms,
    ushort_t* __restrict__ e, float* __restrict__ stats) {
  __shared__ __align__(16) ushort_t eT[64 * 136];  // 17.4 KB
  __shared__ float xnL[64], ynL[128], scr[12];
  int t = threadIdx.x;
  int b = blockIdx.z;
  int n0 = blockIdx.x * 64, m0 = blockIdx.y * 128;
  int w = t >> 6, lane = t & 63;

  if (t < 64) xnL[t] = norms[b * N + n0 + t];
  else if (t < 192) ynL[t - 64] = norms[B * N + b * M + m0 + (t - 64)];

  int wr = (w >> 1) * 32, wc = (w & 1) * 64;  // wave sub-tile origin
  int fr = lane & 15, fk = (lane >> 4) * 8;

  f32x4 acc[2][4];
#pragma unroll
  for (int i = 0; i < 2; i++)
#pragma unroll
    for (int j = 0; j < 4; j++) acc[i][j] = (f32x4){0.f, 0.f, 0.f, 0.f};

  const ushort_t* xb = qwh + (size_t)(b * N + n0 + wr + fr) * 64 + fk;
  const ushort_t* yb = qwh + (size_t)(B * N + b * M + m0 + wc + fr) * 64 + fk;
#pragma unroll
  for (int kg = 0; kg < 2; kg++) {
    bf16x8 aF[2], bF[4];
#pragma unroll
    for (int i = 0; i < 2; i++)
      aF[i] = *(const bf16x8*)(xb + (size_t)i * 16 * 64 + kg * 32);
#pragma unroll
    for (int j = 0; j < 4; j++)
      bF[j] = *(const bf16x8*)(yb + (size_t)j * 16 * 64 + kg * 32);
#pragma unroll
    for (int i = 0; i < 2; i++)
#pragma unroll
      for (int j = 0; j < 4; j++)
        acc[i][j] = __builtin_amdgcn_mfma_f32_16x16x32_bf16(
            aF[i], bF[j], acc[i][j], 0, 0, 0);
  }
  __syncthreads();  // xnL/ynL ready

  float lsum = 0.0f, lsq = 0.0f, lmax = 0.0f;
#pragma unroll
  for (int i = 0; i < 2; i++) {
    int rl = wr + i * 16 + ((lane >> 4) << 2);
    float xn0 = xnL[rl], xn1 = xnL[rl + 1], xn2 = xnL[rl + 2], xn3 = xnL[rl + 3];
#pragma unroll
    for (int j = 0; j < 4; j++) {
      int cl = wc + j * 16 + fr;
      float yn_ = ynL[cl];
      float v0 = __expf(-(xn0 + yn_ - 2.0f * acc[i][j][0]));
      float v1 = __expf(-(xn1 + yn_ - 2.0f * acc[i][j][1]));
      float v2 = __expf(-(xn2 + yn_ - 2.0f * acc[i][j][2]));
      float v3 = __expf(-(xn3 + yn_ - 2.0f * acc[i][j][3]));
      lsum += (v0 + v1) + (v2 + v3);
      lsq += (v0 * v0 + v1 * v1) + (v2 * v2 + v3 * v3);
      lmax = fmaxf(fmaxf(lmax, fmaxf(v0, v1)), fmaxf(v2, v3));
      eT[(rl + 0) * 136 + cl] = (ushort_t)bf16rn(v0);
      eT[(rl + 1) * 136 + cl] = (ushort_t)bf16rn(v1);
      eT[(rl + 2) * 136 + cl] = (ushort_t)bf16rn(v2);
      eT[(rl + 3) * 136 + cl] = (ushort_t)bf16rn(v3);
    }
  }
#pragma unroll
  for (int off = 32; off; off >>= 1) {
    lsum += __shfl_xor(lsum, off, 64);
    lsq += __shfl_xor(lsq, off, 64);
    lmax = fmaxf(lmax, __shfl_xor(lmax, off, 64));
  }
  if (lane == 0) { scr[w] = lsum; scr[4 + w] = lsq; scr[8 + w] = lmax; }
  __syncthreads();  // eT + scr ready

  // coalesced write-out: 16 lanes cover one row's 128 shorts (16 B each)
#pragma unroll
  for (int p = 0; p < 4; p++) {
    int row = p * 16 + (t >> 4);
    int cs = (t & 15) * 8;
    uint4 vv = *(const uint4*)&eT[row * 136 + cs];
    *(uint4*)(e + (size_t)(b * N + n0 + row) * M + m0 + cs) = vv;
  }
  if (t == 0) {
    float ssum = scr[0] + scr[1] + scr[2] + scr[3];
    float ssq = scr[4] + scr[5] + scr[6] + scr[7];
    float smax = fmaxf(fmaxf(scr[8], scr[9]), fmaxf(scr[10], scr[11]));
    atomicAdd(&stats[b * 4 + 0], ssum);
    atomicAdd(&stats[b * 4 + 1], ssq);
    atomicMax((unsigned int*)&stats[b * 4 + 2], __float_as_uint(smax));
  }
}

// ---------------------------------------------------------------------------
// Kernel 3: per-batch params + zero the three colsum rotation buffers.
// ---------------------------------------------------------------------------
__global__ void params_csinit_kernel(const float* __restrict__ stats,
                                     const float* __restrict__ in_w,
                                     const float* __restrict__ in_b,
                                     float* __restrict__ params,
                                     float* __restrict__ csb) {
  int g = blockIdx.x * 256 + threadIdx.x;
  *(float4*)(csb + g * 4) = float4{0.f, 0.f, 0.f, 0.f};
  if (blockIdx.x == 0 && threadIdx.x < B) {
    int b = threadIdx.x;
    float NMf = (float)N * (float)M;
    float mean = stats[b * 4 + 0] / NMf;
    float var = stats[b * 4 + 1] / NMf - mean * mean;
    var = fmaxf(var, 0.0f);
    float stdv = sqrtf(var + EPS_IN);
    float s = in_w[0] / stdv;
    float t = in_b[0] - mean * s;
    float emax = __uint_as_float(((const unsigned int*)stats)[b * 4 + 2]);
    float Amax = fmaxf(fmaf(s, emax, t), t);
    float KK = fmaxf(Amax - 60.0f, 0.0f);
    params[b * 8 + 0] = s * LOG2E;
    params[b * 8 + 1] = (t - 2.0f * KK) * LOG2E;
    params[b * 8 + 2] = KK;
    params[b * 8 + 3] = __expf(-KK);
    params[b * 8 + 4] = __expf(KK);
  }
}

// ---------------------------------------------------------------------------
// Kernel 5: fused sinkhorn iteration (round-12-proven version, reverted
// byte-for-byte: permuted colA/colB conflict-free combine + Ds LDS).
// ---------------------------------------------------------------------------
#define PASS1(uu, off, PA, PB)                           \
  {                                                      \
    float4 ca = *(const float4*)&C2a[(off) + ln4];       \
    float4 cb = *(const float4*)&C2b[(off) + ln4];       \
    PA.x = fexp2(fmaf(blo(uu.x), sL, ca.x));             \
    PA.y = fexp2(fmaf(bhi(uu.x), sL, ca.y));             \
    PA.z = fexp2(fmaf(blo(uu.y), sL, ca.z));             \
    PA.w = fexp2(fmaf(bhi(uu.y), sL, ca.w));             \
    PB.x = fexp2(fmaf(blo(uu.z), sL, cb.x));             \
    PB.y = fexp2(fmaf(bhi(uu.z), sL, cb.y));             \
    PB.z = fexp2(fmaf(blo(uu.w), sL, cb.z));             \
    PB.w = fexp2(fmaf(bhi(uu.w), sL, cb.w));             \
    s0 += PA.x + PB.x;                                   \
    s1 += PA.y + PB.y;                                   \
    s2 += PA.z + PB.z;                                   \
    s3 += PA.w + PB.w;                                   \
  }

#define PASS2(PA, PB, AA, BB)                            \
  {                                                      \
    AA.x = fmaf(PA.x, g, AA.x);                          \
    AA.y = fmaf(PA.y, g, AA.y);                          \
    AA.z = fmaf(PA.z, g, AA.z);                          \
    AA.w = fmaf(PA.w, g, AA.w);                          \
    BB.x = fmaf(PB.x, g, BB.x);                          \
    BB.y = fmaf(PB.y, g, BB.y);                          \
    BB.z = fmaf(PB.z, g, BB.z);                          \
    BB.w = fmaf(PB.w, g, BB.w);                          \
  }

__global__ __launch_bounds__(256) void sink_pass(
    const ushort_t* __restrict__ e, const float* __restrict__ params,
    const float* __restrict__ cs_cur, float* __restrict__ cs_nxt,
    float* __restrict__ cs_zz, float* __restrict__ R) {
  __shared__ __align__(16) float C2a[1024], C2b[1024];
  __shared__ __align__(16) float Ds[2048];
  __shared__ __align__(16) float colA[1024], colB[1024];
  int t = threadIdx.x;
  int b = blockIdx.y, blk = blockIdx.x;  // blk 0..255
  int w = t >> 6, lane = t & 63;
  int ln4 = lane * 4;
  const float* pr = params + b * 8;
  float sL = pr[0], c0L = pr[1], KK = pr[2], enk = pr[3], ekk = pr[4];

  // issue both rows' e-loads FIRST: latency hides under the prologue
  int r0 = blk * 8 + w * 2;
  const ushort_t* ep = e + (size_t)(b * N + r0) * M + lane * 8;
  uint4 u0 = *(const uint4*)(ep);
  uint4 u1 = *(const uint4*)(ep + 512);
  uint4 u2 = *(const uint4*)(ep + 1024);
  uint4 u3 = *(const uint4*)(ep + 1536);
  const ushort_t* ep2 = ep + M;
  uint4 v0 = *(const uint4*)(ep2);
  uint4 v1 = *(const uint4*)(ep2 + 512);
  uint4 v2 = *(const uint4*)(ep2 + 1024);
  uint4 v3 = *(const uint4*)(ep2 + 1536);

  if (blk == 0) {  // coalesced zero of next iteration's accumulator
#pragma unroll
    for (int k = 0; k < 2; k++)
      *(float4*)(cs_zz + b * M + (k * 256 + t) * 4) = float4{0.f, 0.f, 0.f, 0.f};
  }
  {  // prologue: thread t owns columns [t*8, t*8+8)
    float4 c0 = *(const float4*)(cs_cur + b * M + t * 8);
    float4 c1 = *(const float4*)(cs_cur + b * M + t * 8 + 4);
    c0.x += enk; c0.y += enk; c0.z += enk; c0.w += enk;
    c1.x += enk; c1.y += enk; c1.z += enk; c1.w += enk;
    float4 ca, cb;
    ca.x = c0L - flog2(c0.x); ca.y = c0L - flog2(c0.y);
    ca.z = c0L - flog2(c0.z); ca.w = c0L - flog2(c0.w);
    cb.x = c0L - flog2(c1.x); cb.y = c0L - flog2(c1.y);
    cb.z = c0L - flog2(c1.z); cb.w = c0L - flog2(c1.w);
    *(float4*)&C2a[w * 256 + ln4] = ca;
    *(float4*)&C2b[w * 256 + ln4] = cb;
    float4 d0 = {ekk * c0.x, ekk * c0.y, ekk * c0.z, ekk * c0.w};
    float4 d1 = {ekk * c1.x, ekk * c1.y, ekk * c1.z, ekk * c1.w};
    *(float4*)&Ds[t * 8] = d0;  // Ds is plain column-indexed
    *(float4*)&Ds[t * 8 + 4] = d1;
  }
  __syncthreads();

  float4 accA0 = {0,0,0,0}, accA1 = {0,0,0,0}, accA2 = {0,0,0,0}, accA3 = {0,0,0,0};
  float4 accB0 = {0,0,0,0}, accB1 = {0,0,0,0}, accB2 = {0,0,0,0}, accB3 = {0,0,0,0};
  float4 pA0, pA1, pA2, pA3, pB0, pB1, pB2, pB3;

  // ---- row 0 ----
  {
    float s0 = 0, s1 = 0, s2 = 0, s3 = 0;
    PASS1(u0, 0, pA0, pB0)
    PASS1(u1, 256, pA1, pB1)
    PASS1(u2, 512, pA2, pB2)
    PASS1(u3, 768, pA3, pB3)
    float sum = (s0 + s1) + (s2 + s3);
#pragma unroll
    for (int off = 32; off; off >>= 1) sum += __shfl_xor(sum, off, 64);
    float sumtot = sum + enk;
    float ls = flog2(sumtot);
    if (lane == 0) R[b * N + r0] = KK + LN2 * ls;
    float g = fexp2(-KK * LOG2E - ls);  // g = enk/sumtot
    PASS2(pA0, pB0, accA0, accB0)
    PASS2(pA1, pB1, accA1, accB1)
    PASS2(pA2, pB2, accA2, accB2)
    PASS2(pA3, pB3, accA3, accB3)
  }
  // ---- row 1 ----
  {
    float s0 = 0, s1 = 0, s2 = 0, s3 = 0;
    PASS1(v0, 0, pA0, pB0)
    PASS1(v1, 256, pA1, pB1)
    PASS1(v2, 512, pA2, pB2)
    PASS1(v3, 768, pA3, pB3)
    float sum = (s0 + s1) + (s2 + s3);
#pragma unroll
    for (int off = 32; off; off >>= 1) sum += __shfl_xor(sum, off, 64);
    float sumtot = sum + enk;
    float ls = flog2(sumtot);
    if (lane == 0) R[b * N + r0 + 1] = KK + LN2 * ls;
    float g = fexp2(-KK * LOG2E - ls);
    PASS2(pA0, pB0, accA0, accB0)
    PASS2(pA1, pB1, accA1, accB1)
    PASS2(pA2, pB2, accA2, accB2)
    PASS2(pA3, pB3, accA3, accB3)
  }

  // combine the 4 waves' column partials in LDS (permuted layout)
  for (int ww = 0; ww < 4; ww++) {
    if (w == ww) {
      if (ww == 0) {
        *(float4*)&colA[ln4] = accA0;
        *(float4*)&colA[256 + ln4] = accA1;
        *(float4*)&colA[512 + ln4] = accA2;
        *(float4*)&colA[768 + ln4] = accA3;
        *(float4*)&colB[ln4] = accB0;
        *(float4*)&colB[256 + ln4] = accB1;
        *(float4*)&colB[512 + ln4] = accB2;
        *(float4*)&colB[768 + ln4] = accB3;
      } else {
        float4 q;
        q = *(float4*)&colA[ln4];
        q.x += accA0.x; q.y += accA0.y; q.z += accA0.z; q.w += accA0.w;
        *(float4*)&colA[ln4] = q;
        q = *(float4*)&colA[256 + ln4];
        q.x += accA1.x; q.y += accA1.y; q.z += accA1.z; q.w += accA1.w;
        *(float4*)&colA[256 + ln4] = q;
        q = *(float4*)&colA[512 + ln4];
        q.x += accA2.x; q.y += accA2.y; q.z += accA2.z; q.w += accA2.w;
        *(float4*)&colA[512 + ln4] = q;
        q = *(float4*)&colA[768 + ln4];
        q.x += accA3.x; q.y += accA3.y; q.z += accA3.z; q.w += accA3.w;
        *(float4*)&colA[768 + ln4] = q;
        q = *(float4*)&colB[ln4];
        q.x += accB0.x; q.y += accB0.y; q.z += accB0.z; q.w += accB0.w;
        *(float4*)&colB[ln4] = q;
        q = *(float4*)&colB[256 + ln4];
        q.x += accB1.x; q.y += accB1.y; q.z += accB1.z; q.w += accB1.w;
        *(float4*)&colB[256 + ln4] = q;
        q = *(float4*)&colB[512 + ln4];
        q.x += accB2.x; q.y += accB2.y; q.z += accB2.z; q.w += accB2.w;
        *(float4*)&colB[512 + ln4] = q;
        q = *(float4*)&colB[768 + ln4];
        q.x += accB3.x; q.y += accB3.y; q.z += accB3.z; q.w += accB3.w;
        *(float4*)&colB[768 + ln4] = q;
      }
    }
    __syncthreads();
  }
  {  // epilogue: WAVE-COALESCED atomics; thread t owns columns {k*256+t}.
    int q = t & 7;
    const float* srcb = (q < 4) ? colA : colB;
    int qq = q & 3;
#pragma unroll
    for (int k = 0; k < 8; k++) {
      int j = k * 256 + t;
      int idx = (j >> 9) * 256 + ((j >> 3) & 63) * 4 + qq;
      atomicAdd(&cs_nxt[b * M + j], srcb[idx] * Ds[j]);
    }
  }
}

// ---------------------------------------------------------------------------
// Kernel 7: aw[i] = exp2(max_j fma(e,sL,C2L_j) + (KK - R_i)*log2e).
// ---------------------------------------------------------------------------
__global__ __launch_bounds__(256) void awmax_kernel(
    const ushort_t* __restrict__ e, const float* __restrict__ params,
    const float* __restrict__ cs_fin, const float* __restrict__ R,
    float* __restrict__ aw) {
  __shared__ __align__(16) float C2a[1024], C2b[1024];
  int t = threadIdx.x;
  int b = blockIdx.y, blk = blockIdx.x;
  const float* pr = params + b * 8;
  float sL = pr[0], c0L = pr[1], KK = pr[2], enk = pr[3];
  {
    float4 v0 = *(const float4*)(cs_fin + b * M + t * 8);
    float4 v1 = *(const float4*)(cs_fin + b * M + t * 8 + 4);
    float4 ca, cb;
    ca.x = c0L - flog2(v0.x + enk); ca.y = c0L - flog2(v0.y + enk);
    ca.z = c0L - flog2(v0.z + enk); ca.w = c0L - flog2(v0.w + enk);
    cb.x = c0L - flog2(v1.x + enk); cb.y = c0L - flog2(v1.y + enk);
    cb.z = c0L - flog2(v1.z + enk); cb.w = c0L - flog2(v1.w + enk);
    int it = t >> 6, ln = t & 63;
    *(float4*)&C2a[it * 256 + ln * 4] = ca;
    *(float4*)&C2b[it * 256 + ln * 4] = cb;
  }
  __syncthreads();

  int w = t >> 6, lane = t & 63;
  int ln4 = lane * 4;
  int r0 = blk * 16 + w * 4;
  const ushort_t* erow = e + (size_t)(b * N + r0) * M;
#pragma unroll
  for (int rr = 0; rr < 4; rr++) {
    float mx = -3.4e38f;
#pragma unroll
    for (int it = 0; it < 4; it++) {
      uint4 u = *(const uint4*)(erow + (size_t)rr * M + it * 512 + lane * 8);
      float4 ca = *(const float4*)&C2a[it * 256 + ln4];
      float4 cb = *(const float4*)&C2b[it * 256 + ln4];
      mx = fmaxf(mx, fmaf(blo(u.x), sL, ca.x));
      mx = fmaxf(mx, fmaf(bhi(u.x), sL, ca.y));
      mx = fmaxf(mx, fmaf(blo(u.y), sL, ca.z));
      mx = fmaxf(mx, fmaf(bhi(u.y), sL, ca.w));
      mx = fmaxf(mx, fmaf(blo(u.z), sL, cb.x));
      mx = fmaxf(mx, fmaf(bhi(u.z), sL, cb.y));
      mx = fmaxf(mx, fmaf(blo(u.w), sL, cb.z));
      mx = fmaxf(mx, fmaf(bhi(u.w), sL, cb.w));
    }
#pragma unroll
    for (int off = 32; off; off >>= 1) mx = fmaxf(mx, __shfl_xor(mx, off, 64));
    if (lane == 0) {
      float Rr = R[b * N + r0 + rr];
      aw[b * N + r0 + rr] = fexp2(mx + (KK - Rr) * LOG2E);
    }
  }
}

// ---------------------------------------------------------------------------
// Kernel 8: out[b,n,m] = aw[b,n] * aw[b,m], float4 stores.
// ---------------------------------------------------------------------------
__global__ __launch_bounds__(256) void outer_kernel(const float* __restrict__ aw,
                                                    float* __restrict__ out) {
  size_t idx = (size_t)blockIdx.x * 256 + threadIdx.x;
  int b = (int)(idx >> 20);
  size_t rem = idx & ((1u << 20) - 1);
  int n = (int)(rem >> 9);
  int m4 = (int)(rem & 511) << 2;
  float a = aw[b * N + n];
  float4 wv = *(const float4*)(aw + b * N + m4);
  float4 o = {a * wv.x, a * wv.y, a * wv.z, a * wv.w};
  *(float4*)(out + (idx << 2)) = o;
}

// ---------------------------------------------------------------------------
extern "C" void kernel_launch(void* const* d_in, const int* in_sizes, int n_in,
                              void* d_out, int out_size, void* d_ws, size_t ws_size,
                              hipStream_t stream) {
  const float* x = (const float*)d_in[0];
  const float* y = (const float*)d_in[1];
  const float* Wq = (const float*)d_in[2];
  const float* bq = (const float*)d_in[3];
  const float* in_w = (const float*)d_in[4];
  const float* in_b = (const float*)d_in[5];
  ushort_t* e = (ushort_t*)d_out;  // 33.5 MB bf16 scratch; overwritten by outer

  float* ws = (float*)d_ws;
  ushort_t* qwh = (ushort_t*)ws;     // 16384*64 bf16 (occupies 524288 f32)
  float* norms = ws + 1048576;       // 16384
  float* R = norms + 16384;          // 8192
  float* csb0 = R + 8192;            // 8192
  float* csb1 = csb0 + 8192;         // 8192
  float* csb2 = csb1 + 8192;         // 8192
  float* aw = csb2 + 8192;           // 8192
  float* stats = aw + 8192;          // 32
  float* params = stats + 32;        // 32
  ushort_t* wqh = (ushort_t*)(params + 32);  // 64*512 bf16
  float* csb[3] = {csb0, csb1, csb2};

  wqconv_kernel<<<32, 256, 0, stream>>>(Wq, wqh);
  proj_kernel<<<256, 256, 0, stream>>>(x, y, wqh, bq, qwh, norms, stats);
  dist_kernel<<<dim3(32, 16, B), 256, 0, stream>>>(qwh, norms, e, stats);
  params_csinit_kernel<<<24, 256, 0, stream>>>(stats, in_w, in_b, params, csb0);

  for (int it = 0; it < ITERS; it++) {
    sink_pass<<<dim3(256, B), 256, 0, stream>>>(
        e, params, csb[it % 3], csb[(it + 1) % 3], csb[(it + 2) % 3], R);
  }
  awmax_kernel<<<dim3(128, B), 256, 0, stream>>>(e, params, csb[ITERS % 3], R, aw);
  outer_kernel<<<16384, 256, 0, stream>>>(aw, (float*)d_out);
}

// Round 16
// 388.630 us; speedup vs baseline: 1.1616x; 1.0972x over previous
//
#include <hip/hip_runtime.h>
#include <hip/hip_bf16.h>

// Problem constants
constexpr int B = 4, N = 2048, M = 2048, H = 512, ITERS = 20;
constexpr float EPS_IN = 1e-5f;
constexpr float LOG2E = 1.4426950408889634f;
constexpr float LN2 = 0.6931471805599453f;

typedef unsigned short ushort_t;
typedef unsigned int uint_t;
typedef __attribute__((ext_vector_type(8))) short bf16x8;
typedef __attribute__((ext_vector_type(4))) float f32x4;

__device__ __forceinline__ float fexp2(float x) { return __builtin_amdgcn_exp2f(x); }
__device__ __forceinline__ float flog2(float x) { return __builtin_amdgcn_logf(x); }
__device__ __forceinline__ float blo(uint_t v) { return __uint_as_float(v << 16); }
__device__ __forceinline__ float bhi(uint_t v) { return __uint_as_float(v & 0xffff0000u); }
// round-to-nearest-even f32 -> bf16 (inputs finite)
__device__ __forceinline__ uint_t bf16rn(float f) {
  uint_t x = __float_as_uint(f);
  return (x + 0x7fffu + ((x >> 16) & 1u)) >> 16;
}

// ---------------------------------------------------------------------------
// Kernel 0: Wq f32 [64][512] -> bf16 wqh (row-major, L2-resident for proj).
// ---------------------------------------------------------------------------
__global__ __launch_bounds__(256) void wqconv_kernel(
    const float* __restrict__ Wq, ushort_t* __restrict__ wqh) {
  int g = blockIdx.x * 256 + threadIdx.x;  // 0..8191, 4 elems each
  float4 v = *(const float4*)(Wq + (size_t)g * 4);
  uint2 pk;
  pk.x = bf16rn(v.x) | (bf16rn(v.y) << 16);
  pk.y = bf16rn(v.z) | (bf16rn(v.w) << 16);
  *(uint2*)(wqh + (size_t)g * 4) = pk;
}

// ---------------------------------------------------------------------------
// Kernel 1 (MFMA): projections -> qwh[row][k] (16384 x 64 bf16) + f32 norms.
// (round-14-proven)
// ---------------------------------------------------------------------------
__global__ __launch_bounds__(256) void proj_kernel(
    const float* __restrict__ x, const float* __restrict__ y,
    const ushort_t* __restrict__ wqh, const float* __restrict__ bq,
    ushort_t* __restrict__ qwh, float* __restrict__ norms,
    float* __restrict__ stats) {
  int t = threadIdx.x;
  if (blockIdx.x == 0 && t < 32) stats[t] = 0.0f;
  int w = t >> 6, lane = t & 63;
  int fr = lane & 15, fh = (lane >> 4) * 8;
  int rw = blockIdx.x * 64 + w * 16;
  int row = rw + fr;
  const float* src = (row < B * N) ? x + (size_t)row * H
                                   : y + (size_t)(row - B * N) * H;

  f32x4 acc[4];
#pragma unroll
  for (int j = 0; j < 4; j++) acc[j] = (f32x4){0.f, 0.f, 0.f, 0.f};

#pragma unroll
  for (int ks = 0; ks < 16; ks++) {
    float4 a0 = *(const float4*)(src + ks * 32 + fh);
    float4 a1 = *(const float4*)(src + ks * 32 + fh + 4);
    union { uint4 u; bf16x8 h; } ac;
    ac.u.x = bf16rn(a0.x) | (bf16rn(a0.y) << 16);
    ac.u.y = bf16rn(a0.z) | (bf16rn(a0.w) << 16);
    ac.u.z = bf16rn(a1.x) | (bf16rn(a1.y) << 16);
    ac.u.w = bf16rn(a1.z) | (bf16rn(a1.w) << 16);
    bf16x8 aF = ac.h;
#pragma unroll
    for (int j = 0; j < 4; j++) {
      bf16x8 bF = *(const bf16x8*)(wqh + (size_t)(j * 16 + fr) * H + ks * 32 + fh);
      acc[j] = __builtin_amdgcn_mfma_f32_16x16x32_bf16(aF, bF, acc[j], 0, 0, 0);
    }
  }

  float bqv[4];
#pragma unroll
  for (int j = 0; j < 4; j++) bqv[j] = bq[j * 16 + fr];

#pragma unroll
  for (int reg = 0; reg < 4; reg++) {
    int r = rw + ((lane >> 4) << 2) + reg;
    float nr = 0.0f;
#pragma unroll
    for (int j = 0; j < 4; j++) {
      float vv = acc[j][reg] + bqv[j];
      qwh[(size_t)r * 64 + j * 16 + fr] = (ushort_t)bf16rn(vv);
      nr = fmaf(vv, vv, nr);
    }
    nr += __shfl_xor(nr, 1, 64);
    nr += __shfl_xor(nr, 2, 64);
    nr += __shfl_xor(nr, 4, 64);
    nr += __shfl_xor(nr, 8, 64);
    if (fr == 0) norms[r] = nr;
  }
}

// ---------------------------------------------------------------------------
// Kernel 2 (MFMA): e[b,n,m] = exp(-dist) -> bf16 in d_out + per-batch stats.
// 128x128 tile, 1024 blocks (round-13-proven: maximizes per-block fragment
// reuse; dist is L2-request-bound, so tile area beats occupancy).
// ---------------------------------------------------------------------------
__global__ __launch_bounds__(256) void dist_kernel(
    const ushort_t* __restrict__ qwh, const float* __restrict__ norms,
    ushort_t* __restrict__ e, float* __restrict__ stats) {
  __shared__ __align__(16) ushort_t eT[128 * 136];  // 34 KB
  __shared__ float xnL[128], ynL[128], scr[12];
  int t = threadIdx.x;
  int b = blockIdx.z;
  int n0 = blockIdx.x * 128, m0 = blockIdx.y * 128;
  int w = t >> 6, lane = t & 63;

  if (t < 128) xnL[t] = norms[b * N + n0 + t];
  else ynL[t - 128] = norms[B * N + b * M + m0 + (t - 128)];

  int wr = (w >> 1) * 64, wc = (w & 1) * 64;
  int fr = lane & 15, fk = (lane >> 4) * 8;

  f32x4 acc[4][4];
#pragma unroll
  for (int i = 0; i < 4; i++)
#pragma unroll
    for (int j = 0; j < 4; j++) acc[i][j] = (f32x4){0.f, 0.f, 0.f, 0.f};

  const ushort_t* xb = qwh + (size_t)(b * N + n0 + wr + fr) * 64 + fk;
  const ushort_t* yb = qwh + (size_t)(B * N + b * M + m0 + wc + fr) * 64 + fk;
#pragma unroll
  for (int kg = 0; kg < 2; kg++) {
    bf16x8 aF[4], bF[4];
#pragma unroll
    for (int i = 0; i < 4; i++) {
      aF[i] = *(const bf16x8*)(xb + (size_t)i * 16 * 64 + kg * 32);
      bF[i] = *(const bf16x8*)(yb + (size_t)i * 16 * 64 + kg * 32);
    }
#pragma unroll
    for (int i = 0; i < 4; i++)
#pragma unroll
      for (int j = 0; j < 4; j++)
        acc[i][j] = __builtin_amdgcn_mfma_f32_16x16x32_bf16(
            aF[i], bF[j], acc[i][j], 0, 0, 0);
  }
  __syncthreads();

  float lsum = 0.0f, lsq = 0.0f, lmax = 0.0f;
#pragma unroll
  for (int i = 0; i < 4; i++) {
    int rl = wr + i * 16 + ((lane >> 4) << 2);
    float xn0 = xnL[rl], xn1 = xnL[rl + 1], xn2 = xnL[rl + 2], xn3 = xnL[rl + 3];
#pragma unroll
    for (int j = 0; j < 4; j++) {
      int cl = wc + j * 16 + (lane & 15);
      float yn_ = ynL[cl];
      float v0 = __expf(-(xn0 + yn_ - 2.0f * acc[i][j][0]));
      float v1 = __expf(-(xn1 + yn_ - 2.0f * acc[i][j][1]));
      float v2 = __expf(-(xn2 + yn_ - 2.0f * acc[i][j][2]));
      float v3 = __expf(-(xn3 + yn_ - 2.0f * acc[i][j][3]));
      lsum += (v0 + v1) + (v2 + v3);
      lsq += (v0 * v0 + v1 * v1) + (v2 * v2 + v3 * v3);
      lmax = fmaxf(fmaxf(lmax, fmaxf(v0, v1)), fmaxf(v2, v3));
      eT[(rl + 0) * 136 + cl] = (ushort_t)bf16rn(v0);
      eT[(rl + 1) * 136 + cl] = (ushort_t)bf16rn(v1);
      eT[(rl + 2) * 136 + cl] = (ushort_t)bf16rn(v2);
      eT[(rl + 3) * 136 + cl] = (ushort_t)bf16rn(v3);
    }
  }
#pragma unroll
  for (int off = 32; off; off >>= 1) {
    lsum += __shfl_xor(lsum, off, 64);
    lsq += __shfl_xor(lsq, off, 64);
    lmax = fmaxf(lmax, __shfl_xor(lmax, off, 64));
  }
  if (lane == 0) { scr[w] = lsum; scr[4 + w] = lsq; scr[8 + w] = lmax; }
  __syncthreads();

#pragma unroll
  for (int p = 0; p < 8; p++) {
    int row = p * 16 + (t >> 4);
    int cs = (t & 15) * 8;
    uint4 vv = *(const uint4*)&eT[row * 136 + cs];
    *(uint4*)(e + (size_t)(b * N + n0 + row) * M + m0 + cs) = vv;
  }
  if (t == 0) {
    float ssum = scr[0] + scr[1] + scr[2] + scr[3];
    float ssq = scr[4] + scr[5] + scr[6] + scr[7];
    float smax = fmaxf(fmaxf(scr[8], scr[9]), fmaxf(scr[10], scr[11]));
    atomicAdd(&stats[b * 4 + 0], ssum);
    atomicAdd(&stats[b * 4 + 1], ssq);
    atomicMax((unsigned int*)&stats[b * 4 + 2], __float_as_uint(smax));
  }
}

// ---------------------------------------------------------------------------
// Kernel 3: per-batch params + zero the three colsum rotation buffers.
// ---------------------------------------------------------------------------
__global__ void params_csinit_kernel(const float* __restrict__ stats,
                                     const float* __restrict__ in_w,
                                     const float* __restrict__ in_b,
                                     float* __restrict__ params,
                                     float* __restrict__ csb) {
  int g = blockIdx.x * 256 + threadIdx.x;
  *(float4*)(csb + g * 4) = float4{0.f, 0.f, 0.f, 0.f};
  if (blockIdx.x == 0 && threadIdx.x < B) {
    int b = threadIdx.x;
    float NMf = (float)N * (float)M;
    float mean = stats[b * 4 + 0] / NMf;
    float var = stats[b * 4 + 1] / NMf - mean * mean;
    var = fmaxf(var, 0.0f);
    float stdv = sqrtf(var + EPS_IN);
    float s = in_w[0] / stdv;
    float t = in_b[0] - mean * s;
    float emax = __uint_as_float(((const unsigned int*)stats)[b * 4 + 2]);
    float Amax = fmaxf(fmaf(s, emax, t), t);
    float KK = fmaxf(Amax - 60.0f, 0.0f);
    params[b * 8 + 0] = s * LOG2E;
    params[b * 8 + 1] = (t - 2.0f * KK) * LOG2E;
    params[b * 8 + 2] = KK;
    params[b * 8 + 3] = __expf(-KK);
    params[b * 8 + 4] = __expf(KK);
  }
}

// ---------------------------------------------------------------------------
// Kernel 5: fused sinkhorn iteration (round-12-proven).
// ---------------------------------------------------------------------------
#define PASS1(uu, off, PA, PB)                           \
  {                                                      \
    float4 ca = *(const float4*)&C2a[(off) + ln4];       \
    float4 cb = *(const float4*)&C2b[(off) + ln4];       \
    PA.x = fexp2(fmaf(blo(uu.x), sL, ca.x));             \
    PA.y = fexp2(fmaf(bhi(uu.x), sL, ca.y));             \
    PA.z = fexp2(fmaf(blo(uu.y), sL, ca.z));             \
    PA.w = fexp2(fmaf(bhi(uu.y), sL, ca.w));             \
    PB.x = fexp2(fmaf(blo(uu.z), sL, cb.x));             \
    PB.y = fexp2(fmaf(bhi(uu.z), sL, cb.y));             \
    PB.z = fexp2(fmaf(blo(uu.w), sL, cb.z));             \
    PB.w = fexp2(fmaf(bhi(uu.w), sL, cb.w));             \
    s0 += PA.x + PB.x;                                   \
    s1 += PA.y + PB.y;                                   \
    s2 += PA.z + PB.z;                                   \
    s3 += PA.w + PB.w;                                   \
  }

#define PASS2(PA, PB, AA, BB)                            \
  {                                                      \
    AA.x = fmaf(PA.x, g, AA.x);                          \
    AA.y = fmaf(PA.y, g, AA.y);                          \
    AA.z = fmaf(PA.z, g, AA.z);                          \
    AA.w = fmaf(PA.w, g, AA.w);                          \
    BB.x = fmaf(PB.x, g, BB.x);                          \
    BB.y = fmaf(PB.y, g, BB.y);                          \
    BB.z = fmaf(PB.z, g, BB.z);                          \
    BB.w = fmaf(PB.w, g, BB.w);                          \
  }

__global__ __launch_bounds__(256) void sink_pass(
    const ushort_t* __restrict__ e, const float* __restrict__ params,
    const float* __restrict__ cs_cur, float* __restrict__ cs_nxt,
    float* __restrict__ cs_zz, float* __restrict__ R) {
  __shared__ __align__(16) float C2a[1024], C2b[1024];
  __shared__ __align__(16) float Ds[2048];
  __shared__ __align__(16) float colA[1024], colB[1024];
  int t = threadIdx.x;
  int b = blockIdx.y, blk = blockIdx.x;  // blk 0..255
  int w = t >> 6, lane = t & 63;
  int ln4 = lane * 4;
  const float* pr = params + b * 8;
  float sL = pr[0], c0L = pr[1], KK = pr[2], enk = pr[3], ekk = pr[4];

  // issue both rows' e-loads FIRST: latency hides under the prologue
  int r0 = blk * 8 + w * 2;
  const ushort_t* ep = e + (size_t)(b * N + r0) * M + lane * 8;
  uint4 u0 = *(const uint4*)(ep);
  uint4 u1 = *(const uint4*)(ep + 512);
  uint4 u2 = *(const uint4*)(ep + 1024);
  uint4 u3 = *(const uint4*)(ep + 1536);
  const ushort_t* ep2 = ep + M;
  uint4 v0 = *(const uint4*)(ep2);
  uint4 v1 = *(const uint4*)(ep2 + 512);
  uint4 v2 = *(const uint4*)(ep2 + 1024);
  uint4 v3 = *(const uint4*)(ep2 + 1536);

  if (blk == 0) {  // coalesced zero of next iteration's accumulator
#pragma unroll
    for (int k = 0; k < 2; k++)
      *(float4*)(cs_zz + b * M + (k * 256 + t) * 4) = float4{0.f, 0.f, 0.f, 0.f};
  }
  {  // prologue: thread t owns columns [t*8, t*8+8)
    float4 c0 = *(const float4*)(cs_cur + b * M + t * 8);
    float4 c1 = *(const float4*)(cs_cur + b * M + t * 8 + 4);
    c0.x += enk; c0.y += enk; c0.z += enk; c0.w += enk;
    c1.x += enk; c1.y += enk; c1.z += enk; c1.w += enk;
    float4 ca, cb;
    ca.x = c0L - flog2(c0.x); ca.y = c0L - flog2(c0.y);
    ca.z = c0L - flog2(c0.z); ca.w = c0L - flog2(c0.w);
    cb.x = c0L - flog2(c1.x); cb.y = c0L - flog2(c1.y);
    cb.z = c0L - flog2(c1.z); cb.w = c0L - flog2(c1.w);
    *(float4*)&C2a[w * 256 + ln4] = ca;
    *(float4*)&C2b[w * 256 + ln4] = cb;
    float4 d0 = {ekk * c0.x, ekk * c0.y, ekk * c0.z, ekk * c0.w};
    float4 d1 = {ekk * c1.x, ekk * c1.y, ekk * c1.z, ekk * c1.w};
    *(float4*)&Ds[t * 8] = d0;  // Ds is plain column-indexed
    *(float4*)&Ds[t * 8 + 4] = d1;
  }
  __syncthreads();

  float4 accA0 = {0,0,0,0}, accA1 = {0,0,0,0}, accA2 = {0,0,0,0}, accA3 = {0,0,0,0};
  float4 accB0 = {0,0,0,0}, accB1 = {0,0,0,0}, accB2 = {0,0,0,0}, accB3 = {0,0,0,0};
  float4 pA0, pA1, pA2, pA3, pB0, pB1, pB2, pB3;

  // ---- row 0 ----
  {
    float s0 = 0, s1 = 0, s2 = 0, s3 = 0;
    PASS1(u0, 0, pA0, pB0)
    PASS1(u1, 256, pA1, pB1)
    PASS1(u2, 512, pA2, pB2)
    PASS1(u3, 768, pA3, pB3)
    float sum = (s0 + s1) + (s2 + s3);
#pragma unroll
    for (int off = 32; off; off >>= 1) sum += __shfl_xor(sum, off, 64);
    float sumtot = sum + enk;
    float ls = flog2(sumtot);
    if (lane == 0) R[b * N + r0] = KK + LN2 * ls;
    float g = fexp2(-KK * LOG2E - ls);  // g = enk/sumtot
    PASS2(pA0, pB0, accA0, accB0)
    PASS2(pA1, pB1, accA1, accB1)
    PASS2(pA2, pB2, accA2, accB2)
    PASS2(pA3, pB3, accA3, accB3)
  }
  // ---- row 1 ----
  {
    float s0 = 0, s1 = 0, s2 = 0, s3 = 0;
    PASS1(v0, 0, pA0, pB0)
    PASS1(v1, 256, pA1, pB1)
    PASS1(v2, 512, pA2, pB2)
    PASS1(v3, 768, pA3, pB3)
    float sum = (s0 + s1) + (s2 + s3);
#pragma unroll
    for (int off = 32; off; off >>= 1) sum += __shfl_xor(sum, off, 64);
    float sumtot = sum + enk;
    float ls = flog2(sumtot);
    if (lane == 0) R[b * N + r0 + 1] = KK + LN2 * ls;
    float g = fexp2(-KK * LOG2E - ls);
    PASS2(pA0, pB0, accA0, accB0)
    PASS2(pA1, pB1, accA1, accB1)
    PASS2(pA2, pB2, accA2, accB2)
    PASS2(pA3, pB3, accA3, accB3)
  }

  // combine the 4 waves' column partials in LDS (permuted layout)
  for (int ww = 0; ww < 4; ww++) {
    if (w == ww) {
      if (ww == 0) {
        *(float4*)&colA[ln4] = accA0;
        *(float4*)&colA[256 + ln4] = accA1;
        *(float4*)&colA[512 + ln4] = accA2;
        *(float4*)&colA[768 + ln4] = accA3;
        *(float4*)&colB[ln4] = accB0;
        *(float4*)&colB[256 + ln4] = accB1;
        *(float4*)&colB[512 + ln4] = accB2;
        *(float4*)&colB[768 + ln4] = accB3;
      } else {
        float4 q;
        q = *(float4*)&colA[ln4];
        q.x += accA0.x; q.y += accA0.y; q.z += accA0.z; q.w += accA0.w;
        *(float4*)&colA[ln4] = q;
        q = *(float4*)&colA[256 + ln4];
        q.x += accA1.x; q.y += accA1.y; q.z += accA1.z; q.w += accA1.w;
        *(float4*)&colA[256 + ln4] = q;
        q = *(float4*)&colA[512 + ln4];
        q.x += accA2.x; q.y += accA2.y; q.z += accA2.z; q.w += accA2.w;
        *(float4*)&colA[512 + ln4] = q;
        q = *(float4*)&colA[768 + ln4];
        q.x += accA3.x; q.y += accA3.y; q.z += accA3.z; q.w += accA3.w;
        *(float4*)&colA[768 + ln4] = q;
        q = *(float4*)&colB[ln4];
        q.x += accB0.x; q.y += accB0.y; q.z += accB0.z; q.w += accB0.w;
        *(float4*)&colB[ln4] = q;
        q = *(float4*)&colB[256 + ln4];
        q.x += accB1.x; q.y += accB1.y; q.z += accB1.z; q.w += accB1.w;
        *(float4*)&colB[256 + ln4] = q;
        q = *(float4*)&colB[512 + ln4];
        q.x += accB2.x; q.y += accB2.y; q.z += accB2.z; q.w += accB2.w;
        *(float4*)&colB[512 + ln4] = q;
        q = *(float4*)&colB[768 + ln4];
        q.x += accB3.x; q.y += accB3.y; q.z += accB3.z; q.w += accB3.w;
        *(float4*)&colB[768 + ln4] = q;
      }
    }
    __syncthreads();
  }
  {  // epilogue: WAVE-COALESCED atomics; thread t owns columns {k*256+t}.
    int q = t & 7;
    const float* srcb = (q < 4) ? colA : colB;
    int qq = q & 3;
#pragma unroll
    for (int k = 0; k < 8; k++) {
      int j = k * 256 + t;
      int idx = (j >> 9) * 256 + ((j >> 3) & 63) * 4 + qq;
      atomicAdd(&cs_nxt[b * M + j], srcb[idx] * Ds[j]);
    }
  }
}

// ---------------------------------------------------------------------------
// Kernel 7: aw[i] = exp2(max_j fma(e,sL,C2L_j) + (KK - R_i)*log2e).
// ---------------------------------------------------------------------------
__global__ __launch_bounds__(256) void awmax_kernel(
    const ushort_t* __restrict__ e, const float* __restrict__ params,
    const float* __restrict__ cs_fin, const float* __restrict__ R,
    float* __restrict__ aw) {
  __shared__ __align__(16) float C2a[1024], C2b[1024];
  int t = threadIdx.x;
  int b = blockIdx.y, blk = blockIdx.x;
  const float* pr = params + b * 8;
  float sL = pr[0], c0L = pr[1], KK = pr[2], enk = pr[3];
  {
    float4 v0 = *(const float4*)(cs_fin + b * M + t * 8);
    float4 v1 = *(const float4*)(cs_fin + b * M + t * 8 + 4);
    float4 ca, cb;
    ca.x = c0L - flog2(v0.x + enk); ca.y = c0L - flog2(v0.y + enk);
    ca.z = c0L - flog2(v0.z + enk); ca.w = c0L - flog2(v0.w + enk);
    cb.x = c0L - flog2(v1.x + enk); cb.y = c0L - flog2(v1.y + enk);
    cb.z = c0L - flog2(v1.z + enk); cb.w = c0L - flog2(v1.w + enk);
    int it = t >> 6, ln = t & 63;
    *(float4*)&C2a[it * 256 + ln * 4] = ca;
    *(float4*)&C2b[it * 256 + ln * 4] = cb;
  }
  __syncthreads();

  int w = t >> 6, lane = t & 63;
  int ln4 = lane * 4;
  int r0 = blk * 16 + w * 4;
  const ushort_t* erow = e + (size_t)(b * N + r0) * M;
#pragma unroll
  for (int rr = 0; rr < 4; rr++) {
    float mx = -3.4e38f;
#pragma unroll
    for (int it = 0; it < 4; it++) {
      uint4 u = *(const uint4*)(erow + (size_t)rr * M + it * 512 + lane * 8);
      float4 ca = *(const float4*)&C2a[it * 256 + ln4];
      float4 cb = *(const float4*)&C2b[it * 256 + ln4];
      mx = fmaxf(mx, fmaf(blo(u.x), sL, ca.x));
      mx = fmaxf(mx, fmaf(bhi(u.x), sL, ca.y));
      mx = fmaxf(mx, fmaf(blo(u.y), sL, ca.z));
      mx = fmaxf(mx, fmaf(bhi(u.y), sL, ca.w));
      mx = fmaxf(mx, fmaf(blo(u.z), sL, cb.x));
      mx = fmaxf(mx, fmaf(bhi(u.z), sL, cb.y));
      mx = fmaxf(mx, fmaf(blo(u.w), sL, cb.z));
      mx = fmaxf(mx, fmaf(bhi(u.w), sL, cb.w));
    }
#pragma unroll
    for (int off = 32; off; off >>= 1) mx = fmaxf(mx, __shfl_xor(mx, off, 64));
    if (lane == 0) {
      float Rr = R[b * N + r0 + rr];
      aw[b * N + r0 + rr] = fexp2(mx + (KK - Rr) * LOG2E);
    }
  }
}

// ---------------------------------------------------------------------------
// Kernel 8: out[b,n,m] = aw[b,n] * aw[b,m], float4 stores.
// ---------------------------------------------------------------------------
__global__ __launch_bounds__(256) void outer_kernel(const float* __restrict__ aw,
                                                    float* __restrict__ out) {
  size_t idx = (size_t)blockIdx.x * 256 + threadIdx.x;
  int b = (int)(idx >> 20);
  size_t rem = idx & ((1u << 20) - 1);
  int n = (int)(rem >> 9);
  int m4 = (int)(rem & 511) << 2;
  float a = aw[b * N + n];
  float4 wv = *(const float4*)(aw + b * N + m4);
  float4 o = {a * wv.x, a * wv.y, a * wv.z, a * wv.w};
  *(float4*)(out + (idx << 2)) = o;
}

// ---------------------------------------------------------------------------
extern "C" void kernel_launch(void* const* d_in, const int* in_sizes, int n_in,
                              void* d_out, int out_size, void* d_ws, size_t ws_size,
                              hipStream_t stream) {
  const float* x = (const float*)d_in[0];
  const float* y = (const float*)d_in[1];
  const float* Wq = (const float*)d_in[2];
  const float* bq = (const float*)d_in[3];
  const float* in_w = (const float*)d_in[4];
  const float* in_b = (const float*)d_in[5];
  ushort_t* e = (ushort_t*)d_out;  // 33.5 MB bf16 scratch; overwritten by outer

  float* ws = (float*)d_ws;
  ushort_t* qwh = (ushort_t*)ws;     // 16384*64 bf16 (occupies 524288 f32)
  float* norms = ws + 1048576;       // 16384
  float* R = norms + 16384;          // 8192
  float* csb0 = R + 8192;            // 8192
  float* csb1 = csb0 + 8192;         // 8192
  float* csb2 = csb1 + 8192;         // 8192
  float* aw = csb2 + 8192;           // 8192
  float* stats = aw + 8192;          // 32
  float* params = stats + 32;        // 32
  ushort_t* wqh = (ushort_t*)(params + 32);  // 64*512 bf16
  float* csb[3] = {csb0, csb1, csb2};

  wqconv_kernel<<<32, 256, 0, stream>>>(Wq, wqh);
  proj_kernel<<<256, 256, 0, stream>>>(x, y, wqh, bq, qwh, norms, stats);
  dist_kernel<<<dim3(16, 16, B), 256, 0, stream>>>(qwh, norms, e, stats);
  params_csinit_kernel<<<24, 256, 0, stream>>>(stats, in_w, in_b, params, csb0);

  for (int it = 0; it < ITERS; it++) {
    sink_pass<<<dim3(256, B), 256, 0, stream>>>(
        e, params, csb[it % 3], csb[(it + 1) % 3], csb[(it + 2) % 3], R);
  }
  awmax_kernel<<<dim3(128, B), 256, 0, stream>>>(e, params, csb[ITERS % 3], R, aw);
  outer_kernel<<<16384, 256, 0, stream>>>(aw, (float*)d_out);
}

// Round 17
// 307.326 us; speedup vs baseline: 1.4689x; 1.2646x over previous
//
#include <hip/hip_runtime.h>
#include <hip/hip_bf16.h>

// Problem constants
constexpr int B = 4, N = 2048, M = 2048, H = 512, ITERS = 20;
constexpr float EPS_IN = 1e-5f;
constexpr float LOG2E = 1.4426950408889634f;
constexpr float LN2 = 0.6931471805599453f;

typedef unsigned short ushort_t;
typedef unsigned int uint_t;
typedef __attribute__((ext_vector_type(8))) short bf16x8;
typedef __attribute__((ext_vector_type(4))) float f32x4;

__device__ __forceinline__ float fexp2(float x) { return __builtin_amdgcn_exp2f(x); }
__device__ __forceinline__ float flog2(float x) { return __builtin_amdgcn_logf(x); }
__device__ __forceinline__ float blo(uint_t v) { return __uint_as_float(v << 16); }
__device__ __forceinline__ float bhi(uint_t v) { return __uint_as_float(v & 0xffff0000u); }
// round-to-nearest-even f32 -> bf16 (inputs finite)
__device__ __forceinline__ uint_t bf16rn(float f) {
  uint_t x = __float_as_uint(f);
  return (x + 0x7fffu + ((x >> 16) & 1u)) >> 16;
}

// ---------------------------------------------------------------------------
// Kernel 0: Wq f32 [64][512] -> bf16 wqh (row-major, L2-resident for proj).
// ---------------------------------------------------------------------------
__global__ __launch_bounds__(256) void wqconv_kernel(
    const float* __restrict__ Wq, ushort_t* __restrict__ wqh) {
  int g = blockIdx.x * 256 + threadIdx.x;  // 0..8191, 4 elems each
  float4 v = *(const float4*)(Wq + (size_t)g * 4);
  uint2 pk;
  pk.x = bf16rn(v.x) | (bf16rn(v.y) << 16);
  pk.y = bf16rn(v.z) | (bf16rn(v.w) << 16);
  *(uint2*)(wqh + (size_t)g * 4) = pk;
}

// ---------------------------------------------------------------------------
// Kernel 1 (MFMA): projections -> qwh[row][k] (16384 x 64 bf16) + f32 norms.
// (round-14-proven)
// ---------------------------------------------------------------------------
__global__ __launch_bounds__(256) void proj_kernel(
    const float* __restrict__ x, const float* __restrict__ y,
    const ushort_t* __restrict__ wqh, const float* __restrict__ bq,
    ushort_t* __restrict__ qwh, float* __restrict__ norms,
    float* __restrict__ stats) {
  int t = threadIdx.x;
  if (blockIdx.x == 0 && t < 32) stats[t] = 0.0f;
  int w = t >> 6, lane = t & 63;
  int fr = lane & 15, fh = (lane >> 4) * 8;
  int rw = blockIdx.x * 64 + w * 16;
  int row = rw + fr;
  const float* src = (row < B * N) ? x + (size_t)row * H
                                   : y + (size_t)(row - B * N) * H;

  f32x4 acc[4];
#pragma unroll
  for (int j = 0; j < 4; j++) acc[j] = (f32x4){0.f, 0.f, 0.f, 0.f};

#pragma unroll
  for (int ks = 0; ks < 16; ks++) {
    float4 a0 = *(const float4*)(src + ks * 32 + fh);
    float4 a1 = *(const float4*)(src + ks * 32 + fh + 4);
    union { uint4 u; bf16x8 h; } ac;
    ac.u.x = bf16rn(a0.x) | (bf16rn(a0.y) << 16);
    ac.u.y = bf16rn(a0.z) | (bf16rn(a0.w) << 16);
    ac.u.z = bf16rn(a1.x) | (bf16rn(a1.y) << 16);
    ac.u.w = bf16rn(a1.z) | (bf16rn(a1.w) << 16);
    bf16x8 aF = ac.h;
#pragma unroll
    for (int j = 0; j < 4; j++) {
      bf16x8 bF = *(const bf16x8*)(wqh + (size_t)(j * 16 + fr) * H + ks * 32 + fh);
      acc[j] = __builtin_amdgcn_mfma_f32_16x16x32_bf16(aF, bF, acc[j], 0, 0, 0);
    }
  }

  float bqv[4];
#pragma unroll
  for (int j = 0; j < 4; j++) bqv[j] = bq[j * 16 + fr];

#pragma unroll
  for (int reg = 0; reg < 4; reg++) {
    int r = rw + ((lane >> 4) << 2) + reg;
    float nr = 0.0f;
#pragma unroll
    for (int j = 0; j < 4; j++) {
      float vv = acc[j][reg] + bqv[j];
      qwh[(size_t)r * 64 + j * 16 + fr] = (ushort_t)bf16rn(vv);
      nr = fmaf(vv, vv, nr);
    }
    nr += __shfl_xor(nr, 1, 64);
    nr += __shfl_xor(nr, 2, 64);
    nr += __shfl_xor(nr, 4, 64);
    nr += __shfl_xor(nr, 8, 64);
    if (fr == 0) norms[r] = nr;
  }
}

// ---------------------------------------------------------------------------
// Kernel 2 (MFMA): e[b,n,m] = exp(-dist) -> bf16 in d_out + per-batch stats.
// 128x128 tile, 1024 blocks (round-13-proven).
// ---------------------------------------------------------------------------
__global__ __launch_bounds__(256) void dist_kernel(
    const ushort_t* __restrict__ qwh, const float* __restrict__ norms,
    ushort_t* __restrict__ e, float* __restrict__ stats) {
  __shared__ __align__(16) ushort_t eT[128 * 136];  // 34 KB
  __shared__ float xnL[128], ynL[128], scr[12];
  int t = threadIdx.x;
  int b = blockIdx.z;
  int n0 = blockIdx.x * 128, m0 = blockIdx.y * 128;
  int w = t >> 6, lane = t & 63;

  if (t < 128) xnL[t] = norms[b * N + n0 + t];
  else ynL[t - 128] = norms[B * N + b * M + m0 + (t - 128)];

  int wr = (w >> 1) * 64, wc = (w & 1) * 64;
  int fr = lane & 15, fk = (lane >> 4) * 8;

  f32x4 acc[4][4];
#pragma unroll
  for (int i = 0; i < 4; i++)
#pragma unroll
    for (int j = 0; j < 4; j++) acc[i][j] = (f32x4){0.f, 0.f, 0.f, 0.f};

  const ushort_t* xb = qwh + (size_t)(b * N + n0 + wr + fr) * 64 + fk;
  const ushort_t* yb = qwh + (size_t)(B * N + b * M + m0 + wc + fr) * 64 + fk;
#pragma unroll
  for (int kg = 0; kg < 2; kg++) {
    bf16x8 aF[4], bF[4];
#pragma unroll
    for (int i = 0; i < 4; i++) {
      aF[i] = *(const bf16x8*)(xb + (size_t)i * 16 * 64 + kg * 32);
      bF[i] = *(const bf16x8*)(yb + (size_t)i * 16 * 64 + kg * 32);
    }
#pragma unroll
    for (int i = 0; i < 4; i++)
#pragma unroll
      for (int j = 0; j < 4; j++)
        acc[i][j] = __builtin_amdgcn_mfma_f32_16x16x32_bf16(
            aF[i], bF[j], acc[i][j], 0, 0, 0);
  }
  __syncthreads();

  float lsum = 0.0f, lsq = 0.0f, lmax = 0.0f;
#pragma unroll
  for (int i = 0; i < 4; i++) {
    int rl = wr + i * 16 + ((lane >> 4) << 2);
    float xn0 = xnL[rl], xn1 = xnL[rl + 1], xn2 = xnL[rl + 2], xn3 = xnL[rl + 3];
#pragma unroll
    for (int j = 0; j < 4; j++) {
      int cl = wc + j * 16 + (lane & 15);
      float yn_ = ynL[cl];
      float v0 = __expf(-(xn0 + yn_ - 2.0f * acc[i][j][0]));
      float v1 = __expf(-(xn1 + yn_ - 2.0f * acc[i][j][1]));
      float v2 = __expf(-(xn2 + yn_ - 2.0f * acc[i][j][2]));
      float v3 = __expf(-(xn3 + yn_ - 2.0f * acc[i][j][3]));
      lsum += (v0 + v1) + (v2 + v3);
      lsq += (v0 * v0 + v1 * v1) + (v2 * v2 + v3 * v3);
      lmax = fmaxf(fmaxf(lmax, fmaxf(v0, v1)), fmaxf(v2, v3));
      eT[(rl + 0) * 136 + cl] = (ushort_t)bf16rn(v0);
      eT[(rl + 1) * 136 + cl] = (ushort_t)bf16rn(v1);
      eT[(rl + 2) * 136 + cl] = (ushort_t)bf16rn(v2);
      eT[(rl + 3) * 136 + cl] = (ushort_t)bf16rn(v3);
    }
  }
#pragma unroll
  for (int off = 32; off; off >>= 1) {
    lsum += __shfl_xor(lsum, off, 64);
    lsq += __shfl_xor(lsq, off, 64);
    lmax = fmaxf(lmax, __shfl_xor(lmax, off, 64));
  }
  if (lane == 0) { scr[w] = lsum; scr[4 + w] = lsq; scr[8 + w] = lmax; }
  __syncthreads();

#pragma unroll
  for (int p = 0; p < 8; p++) {
    int row = p * 16 + (t >> 4);
    int cs = (t & 15) * 8;
    uint4 vv = *(const uint4*)&eT[row * 136 + cs];
    *(uint4*)(e + (size_t)(b * N + n0 + row) * M + m0 + cs) = vv;
  }
  if (t == 0) {
    float ssum = scr[0] + scr[1] + scr[2] + scr[3];
    float ssq = scr[4] + scr[5] + scr[6] + scr[7];
    float smax = fmaxf(fmaxf(scr[8], scr[9]), fmaxf(scr[10], scr[11]));
    atomicAdd(&stats[b * 4 + 0], ssum);
    atomicAdd(&stats[b * 4 + 1], ssq);
    atomicMax((unsigned int*)&stats[b * 4 + 2], __float_as_uint(smax));
  }
}

// ---------------------------------------------------------------------------
// Kernel 3: per-batch params + zero the three colsum rotation buffers.
// ---------------------------------------------------------------------------
__global__ void params_csinit_kernel(const float* __restrict__ stats,
                                     const float* __restrict__ in_w,
                                     const float* __restrict__ in_b,
                                     float* __restrict__ params,
                                     float* __restrict__ csb) {
  int g = blockIdx.x * 256 + threadIdx.x;
  *(float4*)(csb + g * 4) = float4{0.f, 0.f, 0.f, 0.f};
  if (blockIdx.x == 0 && threadIdx.x < B) {
    int b = threadIdx.x;
    float NMf = (float)N * (float)M;
    float mean = stats[b * 4 + 0] / NMf;
    float var = stats[b * 4 + 1] / NMf - mean * mean;
    var = fmaxf(var, 0.0f);
    float stdv = sqrtf(var + EPS_IN);
    float s = in_w[0] / stdv;
    float t = in_b[0] - mean * s;
    float emax = __uint_as_float(((const unsigned int*)stats)[b * 4 + 2]);
    float Amax = fmaxf(fmaf(s, emax, t), t);
    float KK = fmaxf(Amax - 60.0f, 0.0f);
    params[b * 8 + 0] = s * LOG2E;
    params[b * 8 + 1] = (t - 2.0f * KK) * LOG2E;
    params[b * 8 + 2] = KK;
    params[b * 8 + 3] = __expf(-KK);
    params[b * 8 + 4] = __expf(KK);
  }
}

// ---------------------------------------------------------------------------
// Kernel 5: fused sinkhorn iteration.  NEW: 4 rows/wave (16 rows/block,
// 128 blocks/batch) -> column-atomic count HALVED (128 adds/col vs 256).
// Rows processed in two pairs; pair-2 loads issued as pair-1 finishes,
// reusing the same named registers (round-9-proven pressure).  Combine +
// coalesced atomic epilogue unchanged (round-12-proven).
// ---------------------------------------------------------------------------
#define PASS1(uu, off, PA, PB)                           \
  {                                                      \
    float4 ca = *(const float4*)&C2a[(off) + ln4];       \
    float4 cb = *(const float4*)&C2b[(off) + ln4];       \
    PA.x = fexp2(fmaf(blo(uu.x), sL, ca.x));             \
    PA.y = fexp2(fmaf(bhi(uu.x), sL, ca.y));             \
    PA.z = fexp2(fmaf(blo(uu.y), sL, ca.z));             \
    PA.w = fexp2(fmaf(bhi(uu.y), sL, ca.w));             \
    PB.x = fexp2(fmaf(blo(uu.z), sL, cb.x));             \
    PB.y = fexp2(fmaf(bhi(uu.z), sL, cb.y));             \
    PB.z = fexp2(fmaf(blo(uu.w), sL, cb.z));             \
    PB.w = fexp2(fmaf(bhi(uu.w), sL, cb.w));             \
    s0 += PA.x + PB.x;                                   \
    s1 += PA.y + PB.y;                                   \
    s2 += PA.z + PB.z;                                   \
    s3 += PA.w + PB.w;                                   \
  }

#define PASS2(PA, PB, AA, BB)                            \
  {                                                      \
    AA.x = fmaf(PA.x, g, AA.x);                          \
    AA.y = fmaf(PA.y, g, AA.y);                          \
    AA.z = fmaf(PA.z, g, AA.z);                          \
    AA.w = fmaf(PA.w, g, AA.w);                          \
    BB.x = fmaf(PB.x, g, BB.x);                          \
    BB.y = fmaf(PB.y, g, BB.y);                          \
    BB.z = fmaf(PB.z, g, BB.z);                          \
    BB.w = fmaf(PB.w, g, BB.w);                          \
  }

// one full row: PASS1 on packed regs, wave reduce, R store, PASS2
#define DO_ROW(q0, q1, q2, q3, ridx)                                   \
  {                                                                    \
    float s0 = 0, s1 = 0, s2 = 0, s3 = 0;                              \
    PASS1(q0, 0, pA0, pB0)                                             \
    PASS1(q1, 256, pA1, pB1)                                           \
    PASS1(q2, 512, pA2, pB2)                                           \
    PASS1(q3, 768, pA3, pB3)                                           \
    float sum = (s0 + s1) + (s2 + s3);                                 \
    _Pragma("unroll")                                                  \
    for (int off = 32; off; off >>= 1) sum += __shfl_xor(sum, off, 64);\
    float sumtot = sum + enk;                                          \
    float ls = flog2(sumtot);                                          \
    if (lane == 0) R[b * N + (ridx)] = KK + LN2 * ls;                  \
    float g = fexp2(-KK * LOG2E - ls);                                 \
    PASS2(pA0, pB0, accA0, accB0)                                      \
    PASS2(pA1, pB1, accA1, accB1)                                      \
    PASS2(pA2, pB2, accA2, accB2)                                      \
    PASS2(pA3, pB3, accA3, accB3)                                      \
  }

__global__ __launch_bounds__(256) void sink_pass(
    const ushort_t* __restrict__ e, const float* __restrict__ params,
    const float* __restrict__ cs_cur, float* __restrict__ cs_nxt,
    float* __restrict__ cs_zz, float* __restrict__ R) {
  __shared__ __align__(16) float C2a[1024], C2b[1024];
  __shared__ __align__(16) float Ds[2048];
  __shared__ __align__(16) float colA[1024], colB[1024];
  int t = threadIdx.x;
  int b = blockIdx.y, blk = blockIdx.x;  // blk 0..127
  int w = t >> 6, lane = t & 63;
  int ln4 = lane * 4;
  const float* pr = params + b * 8;
  float sL = pr[0], c0L = pr[1], KK = pr[2], enk = pr[3], ekk = pr[4];

  // rows r0..r0+3 for this wave; pair-1 loads issued before the prologue
  int r0 = blk * 16 + w * 4;
  const ushort_t* ep = e + (size_t)(b * N + r0) * M + lane * 8;
  uint4 u0 = *(const uint4*)(ep);
  uint4 u1 = *(const uint4*)(ep + 512);
  uint4 u2 = *(const uint4*)(ep + 1024);
  uint4 u3 = *(const uint4*)(ep + 1536);
  const ushort_t* ep2 = ep + M;
  uint4 v0 = *(const uint4*)(ep2);
  uint4 v1 = *(const uint4*)(ep2 + 512);
  uint4 v2 = *(const uint4*)(ep2 + 1024);
  uint4 v3 = *(const uint4*)(ep2 + 1536);

  if (blk == 0) {  // coalesced zero of next iteration's accumulator
#pragma unroll
    for (int k = 0; k < 2; k++)
      *(float4*)(cs_zz + b * M + (k * 256 + t) * 4) = float4{0.f, 0.f, 0.f, 0.f};
  }
  {  // prologue: thread t owns columns [t*8, t*8+8)
    float4 c0 = *(const float4*)(cs_cur + b * M + t * 8);
    float4 c1 = *(const float4*)(cs_cur + b * M + t * 8 + 4);
    c0.x += enk; c0.y += enk; c0.z += enk; c0.w += enk;
    c1.x += enk; c1.y += enk; c1.z += enk; c1.w += enk;
    float4 ca, cb;
    ca.x = c0L - flog2(c0.x); ca.y = c0L - flog2(c0.y);
    ca.z = c0L - flog2(c0.z); ca.w = c0L - flog2(c0.w);
    cb.x = c0L - flog2(c1.x); cb.y = c0L - flog2(c1.y);
    cb.z = c0L - flog2(c1.z); cb.w = c0L - flog2(c1.w);
    *(float4*)&C2a[w * 256 + ln4] = ca;
    *(float4*)&C2b[w * 256 + ln4] = cb;
    float4 d0 = {ekk * c0.x, ekk * c0.y, ekk * c0.z, ekk * c0.w};
    float4 d1 = {ekk * c1.x, ekk * c1.y, ekk * c1.z, ekk * c1.w};
    *(float4*)&Ds[t * 8] = d0;  // Ds is plain column-indexed
    *(float4*)&Ds[t * 8 + 4] = d1;
  }
  __syncthreads();

  float4 accA0 = {0,0,0,0}, accA1 = {0,0,0,0}, accA2 = {0,0,0,0}, accA3 = {0,0,0,0};
  float4 accB0 = {0,0,0,0}, accB1 = {0,0,0,0}, accB2 = {0,0,0,0}, accB3 = {0,0,0,0};
  float4 pA0, pA1, pA2, pA3, pB0, pB1, pB2, pB3;

  DO_ROW(u0, u1, u2, u3, r0)
  {  // refill u-regs with row r0+2 (latency hides under row r0+1 compute)
    const ushort_t* ep3 = ep + 2 * M;
    u0 = *(const uint4*)(ep3);
    u1 = *(const uint4*)(ep3 + 512);
    u2 = *(const uint4*)(ep3 + 1024);
    u3 = *(const uint4*)(ep3 + 1536);
  }
  DO_ROW(v0, v1, v2, v3, r0 + 1)
  {  // refill v-regs with row r0+3
    const ushort_t* ep4 = ep + 3 * M;
    v0 = *(const uint4*)(ep4);
    v1 = *(const uint4*)(ep4 + 512);
    v2 = *(const uint4*)(ep4 + 1024);
    v3 = *(const uint4*)(ep4 + 1536);
  }
  DO_ROW(u0, u1, u2, u3, r0 + 2)
  DO_ROW(v0, v1, v2, v3, r0 + 3)

  // combine the 4 waves' column partials in LDS (permuted layout)
  for (int ww = 0; ww < 4; ww++) {
    if (w == ww) {
      if (ww == 0) {
        *(float4*)&colA[ln4] = accA0;
        *(float4*)&colA[256 + ln4] = accA1;
        *(float4*)&colA[512 + ln4] = accA2;
        *(float4*)&colA[768 + ln4] = accA3;
        *(float4*)&colB[ln4] = accB0;
        *(float4*)&colB[256 + ln4] = accB1;
        *(float4*)&colB[512 + ln4] = accB2;
        *(float4*)&colB[768 + ln4] = accB3;
      } else {
        float4 q;
        q = *(float4*)&colA[ln4];
        q.x += accA0.x; q.y += accA0.y; q.z += accA0.z; q.w += accA0.w;
        *(float4*)&colA[ln4] = q;
        q = *(float4*)&colA[256 + ln4];
        q.x += accA1.x; q.y += accA1.y; q.z += accA1.z; q.w += accA1.w;
        *(float4*)&colA[256 + ln4] = q;
        q = *(float4*)&colA[512 + ln4];
        q.x += accA2.x; q.y += accA2.y; q.z += accA2.z; q.w += accA2.w;
        *(float4*)&colA[512 + ln4] = q;
        q = *(float4*)&colA[768 + ln4];
        q.x += accA3.x; q.y += accA3.y; q.z += accA3.z; q.w += accA3.w;
        *(float4*)&colA[768 + ln4] = q;
        q = *(float4*)&colB[ln4];
        q.x += accB0.x; q.y += accB0.y; q.z += accB0.z; q.w += accB0.w;
        *(float4*)&colB[ln4] = q;
        q = *(float4*)&colB[256 + ln4];
        q.x += accB1.x; q.y += accB1.y; q.z += accB1.z; q.w += accB1.w;
        *(float4*)&colB[256 + ln4] = q;
        q = *(float4*)&colB[512 + ln4];
        q.x += accB2.x; q.y += accB2.y; q.z += accB2.z; q.w += accB2.w;
        *(float4*)&colB[512 + ln4] = q;
        q = *(float4*)&colB[768 + ln4];
        q.x += accB3.x; q.y += accB3.y; q.z += accB3.z; q.w += accB3.w;
        *(float4*)&colB[768 + ln4] = q;
      }
    }
    __syncthreads();
  }
  {  // epilogue: WAVE-COALESCED atomics; thread t owns columns {k*256+t}.
    int q = t & 7;
    const float* srcb = (q < 4) ? colA : colB;
    int qq = q & 3;
#pragma unroll
    for (int k = 0; k < 8; k++) {
      int j = k * 256 + t;
      int idx = (j >> 9) * 256 + ((j >> 3) & 63) * 4 + qq;
      atomicAdd(&cs_nxt[b * M + j], srcb[idx] * Ds[j]);
    }
  }
}

// ---------------------------------------------------------------------------
// Kernel 7: aw[i] = exp2(max_j fma(e,sL,C2L_j) + (KK - R_i)*log2e).
// ---------------------------------------------------------------------------
__global__ __launch_bounds__(256) void awmax_kernel(
    const ushort_t* __restrict__ e, const float* __restrict__ params,
    const float* __restrict__ cs_fin, const float* __restrict__ R,
    float* __restrict__ aw) {
  __shared__ __align__(16) float C2a[1024], C2b[1024];
  int t = threadIdx.x;
  int b = blockIdx.y, blk = blockIdx.x;
  const float* pr = params + b * 8;
  float sL = pr[0], c0L = pr[1], KK = pr[2], enk = pr[3];
  {
    float4 v0 = *(const float4*)(cs_fin + b * M + t * 8);
    float4 v1 = *(const float4*)(cs_fin + b * M + t * 8 + 4);
    float4 ca, cb;
    ca.x = c0L - flog2(v0.x + enk); ca.y = c0L - flog2(v0.y + enk);
    ca.z = c0L - flog2(v0.z + enk); ca.w = c0L - flog2(v0.w + enk);
    cb.x = c0L - flog2(v1.x + enk); cb.y = c0L - flog2(v1.y + enk);
    cb.z = c0L - flog2(v1.z + enk); cb.w = c0L - flog2(v1.w + enk);
    int it = t >> 6, ln = t & 63;
    *(float4*)&C2a[it * 256 + ln * 4] = ca;
    *(float4*)&C2b[it * 256 + ln * 4] = cb;
  }
  __syncthreads();

  int w = t >> 6, lane = t & 63;
  int ln4 = lane * 4;
  int r0 = blk * 16 + w * 4;
  const ushort_t* erow = e + (size_t)(b * N + r0) * M;
#pragma unroll
  for (int rr = 0; rr < 4; rr++) {
    float mx = -3.4e38f;
#pragma unroll
    for (int it = 0; it < 4; it++) {
      uint4 u = *(const uint4*)(erow + (size_t)rr * M + it * 512 + lane * 8);
      float4 ca = *(const float4*)&C2a[it * 256 + ln4];
      float4 cb = *(const float4*)&C2b[it * 256 + ln4];
      mx = fmaxf(mx, fmaf(blo(u.x), sL, ca.x));
      mx = fmaxf(mx, fmaf(bhi(u.x), sL, ca.y));
      mx = fmaxf(mx, fmaf(blo(u.y), sL, ca.z));
      mx = fmaxf(mx, fmaf(bhi(u.y), sL, ca.w));
      mx = fmaxf(mx, fmaf(blo(u.z), sL, cb.x));
      mx = fmaxf(mx, fmaf(bhi(u.z), sL, cb.y));
      mx = fmaxf(mx, fmaf(blo(u.w), sL, cb.z));
      mx = fmaxf(mx, fmaf(bhi(u.w), sL, cb.w));
    }
#pragma unroll
    for (int off = 32; off; off >>= 1) mx = fmaxf(mx, __shfl_xor(mx, off, 64));
    if (lane == 0) {
      float Rr = R[b * N + r0 + rr];
      aw[b * N + r0 + rr] = fexp2(mx + (KK - Rr) * LOG2E);
    }
  }
}

// ---------------------------------------------------------------------------
// Kernel 8: out[b,n,m] = aw[b,n] * aw[b,m], float4 stores.
// ---------------------------------------------------------------------------
__global__ __launch_bounds__(256) void outer_kernel(const float* __restrict__ aw,
                                                    float* __restrict__ out) {
  size_t idx = (size_t)blockIdx.x * 256 + threadIdx.x;
  int b = (int)(idx >> 20);
  size_t rem = idx & ((1u << 20) - 1);
  int n = (int)(rem >> 9);
  int m4 = (int)(rem & 511) << 2;
  float a = aw[b * N + n];
  float4 wv = *(const float4*)(aw + b * N + m4);
  float4 o = {a * wv.x, a * wv.y, a * wv.z, a * wv.w};
  *(float4*)(out + (idx << 2)) = o;
}

// ---------------------------------------------------------------------------
extern "C" void kernel_launch(void* const* d_in, const int* in_sizes, int n_in,
                              void* d_out, int out_size, void* d_ws, size_t ws_size,
                              hipStream_t stream) {
  const float* x = (const float*)d_in[0];
  const float* y = (const float*)d_in[1];
  const float* Wq = (const float*)d_in[2];
  const float* bq = (const float*)d_in[3];
  const float* in_w = (const float*)d_in[4];
  const float* in_b = (const float*)d_in[5];
  ushort_t* e = (ushort_t*)d_out;  // 33.5 MB bf16 scratch; overwritten by outer

  float* ws = (float*)d_ws;
  ushort_t* qwh = (ushort_t*)ws;     // 16384*64 bf16 (occupies 524288 f32)
  float* norms = ws + 1048576;       // 16384
  float* R = norms + 16384;          // 8192
  float* csb0 = R + 8192;            // 8192
  float* csb1 = csb0 + 8192;         // 8192
  float* csb2 = csb1 + 8192;         // 8192
  float* aw = csb2 + 8192;           // 8192
  float* stats = aw + 8192;          // 32
  float* params = stats + 32;        // 32
  ushort_t* wqh = (ushort_t*)(params + 32);  // 64*512 bf16
  float* csb[3] = {csb0, csb1, csb2};

  wqconv_kernel<<<32, 256, 0, stream>>>(Wq, wqh);
  proj_kernel<<<256, 256, 0, stream>>>(x, y, wqh, bq, qwh, norms, stats);
  dist_kernel<<<dim3(16, 16, B), 256, 0, stream>>>(qwh, norms, e, stats);
  params_csinit_kernel<<<24, 256, 0, stream>>>(stats, in_w, in_b, params, csb0);

  for (int it = 0; it < ITERS; it++) {
    sink_pass<<<dim3(128, B), 256, 0, stream>>>(
        e, params, csb[it % 3], csb[(it + 1) % 3], csb[(it + 2) % 3], R);
  }
  awmax_kernel<<<dim3(128, B), 256, 0, stream>>>(e, params, csb[ITERS % 3], R, aw);
  outer_kernel<<<16384, 256, 0, stream>>>(aw, (float*)d_out);
}

// Round 18
// 266.115 us; speedup vs baseline: 1.6963x; 1.1549x over previous
//
#include <hip/hip_runtime.h>
#include <hip/hip_bf16.h>

// Problem constants
constexpr int B = 4, N = 2048, M = 2048, H = 512, ITERS = 20;
constexpr float EPS_IN = 1e-5f;
constexpr float LOG2E = 1.4426950408889634f;
constexpr float LN2 = 0.6931471805599453f;

typedef unsigned short ushort_t;
typedef unsigned int uint_t;
typedef __attribute__((ext_vector_type(8))) short bf16x8;
typedef __attribute__((ext_vector_type(4))) float f32x4;

__device__ __forceinline__ float fexp2(float x) { return __builtin_amdgcn_exp2f(x); }
__device__ __forceinline__ float flog2(float x) { return __builtin_amdgcn_logf(x); }
__device__ __forceinline__ float blo(uint_t v) { return __uint_as_float(v << 16); }
__device__ __forceinline__ float bhi(uint_t v) { return __uint_as_float(v & 0xffff0000u); }
// round-to-nearest-even f32 -> bf16 (inputs finite)
__device__ __forceinline__ uint_t bf16rn(float f) {
  uint_t x = __float_as_uint(f);
  return (x + 0x7fffu + ((x >> 16) & 1u)) >> 16;
}

// ---------------------------------------------------------------------------
// Kernel 0: Wq f32 [64][512] -> bf16 wqh (row-major, L2-resident for proj).
// ---------------------------------------------------------------------------
__global__ __launch_bounds__(256) void wqconv_kernel(
    const float* __restrict__ Wq, ushort_t* __restrict__ wqh) {
  int g = blockIdx.x * 256 + threadIdx.x;  // 0..8191, 4 elems each
  float4 v = *(const float4*)(Wq + (size_t)g * 4);
  uint2 pk;
  pk.x = bf16rn(v.x) | (bf16rn(v.y) << 16);
  pk.y = bf16rn(v.z) | (bf16rn(v.w) << 16);
  *(uint2*)(wqh + (size_t)g * 4) = pk;
}

// ---------------------------------------------------------------------------
// Kernel 1 (MFMA): projections -> qwf in MFMA FRAGMENT ORDER + f32 norms.
// Fragment layout: qwf[(r>>4)*1024 + (k>>3)*128 + (r&15)*8 + (k&7)] — a
// wave's A/B fragment load in dist becomes one contiguous 1 KB block.
// ---------------------------------------------------------------------------
__global__ __launch_bounds__(256) void proj_kernel(
    const float* __restrict__ x, const float* __restrict__ y,
    const ushort_t* __restrict__ wqh, const float* __restrict__ bq,
    ushort_t* __restrict__ qwf, float* __restrict__ norms,
    float* __restrict__ stats) {
  int t = threadIdx.x;
  if (blockIdx.x == 0 && t < 32) stats[t] = 0.0f;
  int w = t >> 6, lane = t & 63;
  int fr = lane & 15, fh = (lane >> 4) * 8;
  int rw = blockIdx.x * 64 + w * 16;
  int row = rw + fr;
  const float* src = (row < B * N) ? x + (size_t)row * H
                                   : y + (size_t)(row - B * N) * H;

  f32x4 acc[4];
#pragma unroll
  for (int j = 0; j < 4; j++) acc[j] = (f32x4){0.f, 0.f, 0.f, 0.f};

#pragma unroll
  for (int ks = 0; ks < 16; ks++) {
    float4 a0 = *(const float4*)(src + ks * 32 + fh);
    float4 a1 = *(const float4*)(src + ks * 32 + fh + 4);
    union { uint4 u; bf16x8 h; } ac;
    ac.u.x = bf16rn(a0.x) | (bf16rn(a0.y) << 16);
    ac.u.y = bf16rn(a0.z) | (bf16rn(a0.w) << 16);
    ac.u.z = bf16rn(a1.x) | (bf16rn(a1.y) << 16);
    ac.u.w = bf16rn(a1.z) | (bf16rn(a1.w) << 16);
    bf16x8 aF = ac.h;
#pragma unroll
    for (int j = 0; j < 4; j++) {
      bf16x8 bF = *(const bf16x8*)(wqh + (size_t)(j * 16 + fr) * H + ks * 32 + fh);
      acc[j] = __builtin_amdgcn_mfma_f32_16x16x32_bf16(aF, bF, acc[j], 0, 0, 0);
    }
  }

  float bqv[4];
#pragma unroll
  for (int j = 0; j < 4; j++) bqv[j] = bq[j * 16 + fr];

  size_t gbase = (size_t)(rw >> 4) * 1024;
#pragma unroll
  for (int reg = 0; reg < 4; reg++) {
    int rr = ((lane >> 4) << 2) + reg;  // r & 15
    int r = rw + rr;
    float nr = 0.0f;
#pragma unroll
    for (int j = 0; j < 4; j++) {
      float vv = acc[j][reg] + bqv[j];
      // col k = j*16 + fr:  k>>3 = j*2 + (fr>>3),  k&7 = fr&7
      qwf[gbase + (size_t)(j * 2 + (fr >> 3)) * 128 + rr * 8 + (fr & 7)] =
          (ushort_t)bf16rn(vv);
      nr = fmaf(vv, vv, nr);
    }
    nr += __shfl_xor(nr, 1, 64);
    nr += __shfl_xor(nr, 2, 64);
    nr += __shfl_xor(nr, 4, 64);
    nr += __shfl_xor(nr, 8, 64);
    if (fr == 0) norms[r] = nr;
  }
}

// ---------------------------------------------------------------------------
// Kernel 2 (MFMA): e[b,n,m] = exp(-dist) -> bf16 in d_out + per-batch stats.
// 128x128 tile.  Fragment loads are now CONTIGUOUS 1 KB wave-loads from the
// fragment-ordered qwf (kills the 32-line/instr scatter: frag addr =
// group*1024 + kg*512 + lane*8).
// ---------------------------------------------------------------------------
__global__ __launch_bounds__(256) void dist_kernel(
    const ushort_t* __restrict__ qwf, const float* __restrict__ norms,
    ushort_t* __restrict__ e, float* __restrict__ stats) {
  __shared__ __align__(16) ushort_t eT[128 * 136];  // 34 KB
  __shared__ float xnL[128], ynL[128], scr[12];
  int t = threadIdx.x;
  int b = blockIdx.z;
  int n0 = blockIdx.x * 128, m0 = blockIdx.y * 128;
  int w = t >> 6, lane = t & 63;

  if (t < 128) xnL[t] = norms[b * N + n0 + t];
  else ynL[t - 128] = norms[B * N + b * M + m0 + (t - 128)];

  int wr = (w >> 1) * 64, wc = (w & 1) * 64;

  f32x4 acc[4][4];
#pragma unroll
  for (int i = 0; i < 4; i++)
#pragma unroll
    for (int j = 0; j < 4; j++) acc[i][j] = (f32x4){0.f, 0.f, 0.f, 0.f};

  const ushort_t* xg = qwf + (size_t)((b * N + n0 + wr) >> 4) * 1024 + lane * 8;
  const ushort_t* yg = qwf + (size_t)((B * N + b * M + m0 + wc) >> 4) * 1024 + lane * 8;
#pragma unroll
  for (int kg = 0; kg < 2; kg++) {
    bf16x8 aF[4], bF[4];
#pragma unroll
    for (int i = 0; i < 4; i++) {
      aF[i] = *(const bf16x8*)(xg + (size_t)i * 1024 + kg * 512);
      bF[i] = *(const bf16x8*)(yg + (size_t)i * 1024 + kg * 512);
    }
#pragma unroll
    for (int i = 0; i < 4; i++)
#pragma unroll
      for (int j = 0; j < 4; j++)
        acc[i][j] = __builtin_amdgcn_mfma_f32_16x16x32_bf16(
            aF[i], bF[j], acc[i][j], 0, 0, 0);
  }
  __syncthreads();

  float lsum = 0.0f, lsq = 0.0f, lmax = 0.0f;
#pragma unroll
  for (int i = 0; i < 4; i++) {
    int rl = wr + i * 16 + ((lane >> 4) << 2);
    float xn0 = xnL[rl], xn1 = xnL[rl + 1], xn2 = xnL[rl + 2], xn3 = xnL[rl + 3];
#pragma unroll
    for (int j = 0; j < 4; j++) {
      int cl = wc + j * 16 + (lane & 15);
      float yn_ = ynL[cl];
      float v0 = __expf(-(xn0 + yn_ - 2.0f * acc[i][j][0]));
      float v1 = __expf(-(xn1 + yn_ - 2.0f * acc[i][j][1]));
      float v2 = __expf(-(xn2 + yn_ - 2.0f * acc[i][j][2]));
      float v3 = __expf(-(xn3 + yn_ - 2.0f * acc[i][j][3]));
      lsum += (v0 + v1) + (v2 + v3);
      lsq += (v0 * v0 + v1 * v1) + (v2 * v2 + v3 * v3);
      lmax = fmaxf(fmaxf(lmax, fmaxf(v0, v1)), fmaxf(v2, v3));
      eT[(rl + 0) * 136 + cl] = (ushort_t)bf16rn(v0);
      eT[(rl + 1) * 136 + cl] = (ushort_t)bf16rn(v1);
      eT[(rl + 2) * 136 + cl] = (ushort_t)bf16rn(v2);
      eT[(rl + 3) * 136 + cl] = (ushort_t)bf16rn(v3);
    }
  }
#pragma unroll
  for (int off = 32; off; off >>= 1) {
    lsum += __shfl_xor(lsum, off, 64);
    lsq += __shfl_xor(lsq, off, 64);
    lmax = fmaxf(lmax, __shfl_xor(lmax, off, 64));
  }
  if (lane == 0) { scr[w] = lsum; scr[4 + w] = lsq; scr[8 + w] = lmax; }
  __syncthreads();

#pragma unroll
  for (int p = 0; p < 8; p++) {
    int row = p * 16 + (t >> 4);
    int cs = (t & 15) * 8;
    uint4 vv = *(const uint4*)&eT[row * 136 + cs];
    *(uint4*)(e + (size_t)(b * N + n0 + row) * M + m0 + cs) = vv;
  }
  if (t == 0) {
    float ssum = scr[0] + scr[1] + scr[2] + scr[3];
    float ssq = scr[4] + scr[5] + scr[6] + scr[7];
    float smax = fmaxf(fmaxf(scr[8], scr[9]), fmaxf(scr[10], scr[11]));
    atomicAdd(&stats[b * 4 + 0], ssum);
    atomicAdd(&stats[b * 4 + 1], ssq);
    atomicMax((unsigned int*)&stats[b * 4 + 2], __float_as_uint(smax));
  }
}

// ---------------------------------------------------------------------------
// Kernel 3: per-batch params + zero the three colsum rotation buffers.
// ---------------------------------------------------------------------------
__global__ void params_csinit_kernel(const float* __restrict__ stats,
                                     const float* __restrict__ in_w,
                                     const float* __restrict__ in_b,
                                     float* __restrict__ params,
                                     float* __restrict__ csb) {
  int g = blockIdx.x * 256 + threadIdx.x;
  *(float4*)(csb + g * 4) = float4{0.f, 0.f, 0.f, 0.f};
  if (blockIdx.x == 0 && threadIdx.x < B) {
    int b = threadIdx.x;
    float NMf = (float)N * (float)M;
    float mean = stats[b * 4 + 0] / NMf;
    float var = stats[b * 4 + 1] / NMf - mean * mean;
    var = fmaxf(var, 0.0f);
    float stdv = sqrtf(var + EPS_IN);
    float s = in_w[0] / stdv;
    float t = in_b[0] - mean * s;
    float emax = __uint_as_float(((const unsigned int*)stats)[b * 4 + 2]);
    float Amax = fmaxf(fmaf(s, emax, t), t);
    float KK = fmaxf(Amax - 60.0f, 0.0f);
    params[b * 8 + 0] = s * LOG2E;
    params[b * 8 + 1] = (t - 2.0f * KK) * LOG2E;
    params[b * 8 + 2] = KK;
    params[b * 8 + 3] = __expf(-KK);
    params[b * 8 + 4] = __expf(KK);
  }
}

// ---------------------------------------------------------------------------
// Kernel 5: fused sinkhorn iteration.  NEW: 512 threads = 8 waves x 4 rows
// (32 rows/block, 64 blocks/batch) -> column atomics halved again (64/col).
// Waves 0-3 combine into colA/colB, waves 4-7 into colA2/colB2 (4 serialized
// rounds, pairs active); epilogue sums both.  LDS 32 KB -> 2 blocks/CU.
// ---------------------------------------------------------------------------
#define PASS1(uu, off, PA, PB)                           \
  {                                                      \
    float4 ca = *(const float4*)&C2a[(off) + ln4];       \
    float4 cb = *(const float4*)&C2b[(off) + ln4];       \
    PA.x = fexp2(fmaf(blo(uu.x), sL, ca.x));             \
    PA.y = fexp2(fmaf(bhi(uu.x), sL, ca.y));             \
    PA.z = fexp2(fmaf(blo(uu.y), sL, ca.z));             \
    PA.w = fexp2(fmaf(bhi(uu.y), sL, ca.w));             \
    PB.x = fexp2(fmaf(blo(uu.z), sL, cb.x));             \
    PB.y = fexp2(fmaf(bhi(uu.z), sL, cb.y));             \
    PB.z = fexp2(fmaf(blo(uu.w), sL, cb.z));             \
    PB.w = fexp2(fmaf(bhi(uu.w), sL, cb.w));             \
    s0 += PA.x + PB.x;                                   \
    s1 += PA.y + PB.y;                                   \
    s2 += PA.z + PB.z;                                   \
    s3 += PA.w + PB.w;                                   \
  }

#define PASS2(PA, PB, AA, BB)                            \
  {                                                      \
    AA.x = fmaf(PA.x, g, AA.x);                          \
    AA.y = fmaf(PA.y, g, AA.y);                          \
    AA.z = fmaf(PA.z, g, AA.z);                          \
    AA.w = fmaf(PA.w, g, AA.w);                          \
    BB.x = fmaf(PB.x, g, BB.x);                          \
    BB.y = fmaf(PB.y, g, BB.y);                          \
    BB.z = fmaf(PB.z, g, BB.z);                          \
    BB.w = fmaf(PB.w, g, BB.w);                          \
  }

// one full row: PASS1 on packed regs, wave reduce, R store, PASS2
#define DO_ROW(q0, q1, q2, q3, ridx)                                   \
  {                                                                    \
    float s0 = 0, s1 = 0, s2 = 0, s3 = 0;                              \
    PASS1(q0, 0, pA0, pB0)                                             \
    PASS1(q1, 256, pA1, pB1)                                           \
    PASS1(q2, 512, pA2, pB2)                                           \
    PASS1(q3, 768, pA3, pB3)                                           \
    float sum = (s0 + s1) + (s2 + s3);                                 \
    _Pragma("unroll")                                                  \
    for (int off = 32; off; off >>= 1) sum += __shfl_xor(sum, off, 64);\
    float sumtot = sum + enk;                                          \
    float ls = flog2(sumtot);                                          \
    if (lane == 0) R[b * N + (ridx)] = KK + LN2 * ls;                  \
    float g = fexp2(-KK * LOG2E - ls);                                 \
    PASS2(pA0, pB0, accA0, accB0)                                      \
    PASS2(pA1, pB1, accA1, accB1)                                      \
    PASS2(pA2, pB2, accA2, accB2)                                      \
    PASS2(pA3, pB3, accA3, accB3)                                      \
  }

#define COMBINE8(cA, cB)                                               \
  {                                                                    \
    float4 q;                                                          \
    q = *(float4*)&cA[ln4];                                            \
    q.x += accA0.x; q.y += accA0.y; q.z += accA0.z; q.w += accA0.w;    \
    *(float4*)&cA[ln4] = q;                                            \
    q = *(float4*)&cA[256 + ln4];                                      \
    q.x += accA1.x; q.y += accA1.y; q.z += accA1.z; q.w += accA1.w;    \
    *(float4*)&cA[256 + ln4] = q;                                      \
    q = *(float4*)&cA[512 + ln4];                                      \
    q.x += accA2.x; q.y += accA2.y; q.z += accA2.z; q.w += accA2.w;    \
    *(float4*)&cA[512 + ln4] = q;                                      \
    q = *(float4*)&cA[768 + ln4];                                      \
    q.x += accA3.x; q.y += accA3.y; q.z += accA3.z; q.w += accA3.w;    \
    *(float4*)&cA[768 + ln4] = q;                                      \
    q = *(float4*)&cB[ln4];                                            \
    q.x += accB0.x; q.y += accB0.y; q.z += accB0.z; q.w += accB0.w;    \
    *(float4*)&cB[ln4] = q;                                            \
    q = *(float4*)&cB[256 + ln4];                                      \
    q.x += accB1.x; q.y += accB1.y; q.z += accB1.z; q.w += accB1.w;    \
    *(float4*)&cB[256 + ln4] = q;                                      \
    q = *(float4*)&cB[512 + ln4];                                      \
    q.x += accB2.x; q.y += accB2.y; q.z += accB2.z; q.w += accB2.w;    \
    *(float4*)&cB[512 + ln4] = q;                                      \
    q = *(float4*)&cB[768 + ln4];                                      \
    q.x += accB3.x; q.y += accB3.y; q.z += accB3.z; q.w += accB3.w;    \
    *(float4*)&cB[768 + ln4] = q;                                      \
  }

#define STORE8(cA, cB)                                                 \
  {                                                                    \
    *(float4*)&cA[ln4] = accA0;                                        \
    *(float4*)&cA[256 + ln4] = accA1;                                  \
    *(float4*)&cA[512 + ln4] = accA2;                                  \
    *(float4*)&cA[768 + ln4] = accA3;                                  \
    *(float4*)&cB[ln4] = accB0;                                        \
    *(float4*)&cB[256 + ln4] = accB1;                                  \
    *(float4*)&cB[512 + ln4] = accB2;                                  \
    *(float4*)&cB[768 + ln4] = accB3;                                  \
  }

__global__ __launch_bounds__(512) void sink_pass(
    const ushort_t* __restrict__ e, const float* __restrict__ params,
    const float* __restrict__ cs_cur, float* __restrict__ cs_nxt,
    float* __restrict__ cs_zz, float* __restrict__ R) {
  __shared__ __align__(16) float C2a[1024], C2b[1024];
  __shared__ __align__(16) float Ds[2048];
  __shared__ __align__(16) float colA[1024], colB[1024];
  __shared__ __align__(16) float colA2[1024], colB2[1024];
  int t = threadIdx.x;          // 0..511
  int b = blockIdx.y, blk = blockIdx.x;  // blk 0..63
  int w = t >> 6, lane = t & 63;
  int ln4 = lane * 4;
  const float* pr = params + b * 8;
  float sL = pr[0], c0L = pr[1], KK = pr[2], enk = pr[3], ekk = pr[4];

  // rows r0..r0+3 for this wave; pair-1 loads issued before the prologue
  int r0 = blk * 32 + w * 4;
  const ushort_t* ep = e + (size_t)(b * N + r0) * M + lane * 8;
  uint4 u0 = *(const uint4*)(ep);
  uint4 u1 = *(const uint4*)(ep + 512);
  uint4 u2 = *(const uint4*)(ep + 1024);
  uint4 u3 = *(const uint4*)(ep + 1536);
  const ushort_t* ep2 = ep + M;
  uint4 v0 = *(const uint4*)(ep2);
  uint4 v1 = *(const uint4*)(ep2 + 512);
  uint4 v2 = *(const uint4*)(ep2 + 1024);
  uint4 v3 = *(const uint4*)(ep2 + 1536);

  if (blk == 0) {  // coalesced zero of next iteration's accumulator
    *(float4*)(cs_zz + b * M + t * 4) = float4{0.f, 0.f, 0.f, 0.f};
  }
  if (t < 256) {  // prologue: thread t owns columns [t*8, t*8+8)
    float4 c0 = *(const float4*)(cs_cur + b * M + t * 8);
    float4 c1 = *(const float4*)(cs_cur + b * M + t * 8 + 4);
    c0.x += enk; c0.y += enk; c0.z += enk; c0.w += enk;
    c1.x += enk; c1.y += enk; c1.z += enk; c1.w += enk;
    float4 ca, cb;
    ca.x = c0L - flog2(c0.x); ca.y = c0L - flog2(c0.y);
    ca.z = c0L - flog2(c0.z); ca.w = c0L - flog2(c0.w);
    cb.x = c0L - flog2(c1.x); cb.y = c0L - flog2(c1.y);
    cb.z = c0L - flog2(c1.z); cb.w = c0L - flog2(c1.w);
    *(float4*)&C2a[w * 256 + ln4] = ca;
    *(float4*)&C2b[w * 256 + ln4] = cb;
    float4 d0 = {ekk * c0.x, ekk * c0.y, ekk * c0.z, ekk * c0.w};
    float4 d1 = {ekk * c1.x, ekk * c1.y, ekk * c1.z, ekk * c1.w};
    *(float4*)&Ds[t * 8] = d0;  // Ds is plain column-indexed
    *(float4*)&Ds[t * 8 + 4] = d1;
  }
  __syncthreads();

  float4 accA0 = {0,0,0,0}, accA1 = {0,0,0,0}, accA2 = {0,0,0,0}, accA3 = {0,0,0,0};
  float4 accB0 = {0,0,0,0}, accB1 = {0,0,0,0}, accB2 = {0,0,0,0}, accB3 = {0,0,0,0};
  float4 pA0, pA1, pA2, pA3, pB0, pB1, pB2, pB3;

  DO_ROW(u0, u1, u2, u3, r0)
  {  // refill u-regs with row r0+2 (latency hides under row r0+1 compute)
    const ushort_t* ep3 = ep + 2 * M;
    u0 = *(const uint4*)(ep3);
    u1 = *(const uint4*)(ep3 + 512);
    u2 = *(const uint4*)(ep3 + 1024);
    u3 = *(const uint4*)(ep3 + 1536);
  }
  DO_ROW(v0, v1, v2, v3, r0 + 1)
  {  // refill v-regs with row r0+3
    const ushort_t* ep4 = ep + 3 * M;
    v0 = *(const uint4*)(ep4);
    v1 = *(const uint4*)(ep4 + 512);
    v2 = *(const uint4*)(ep4 + 1024);
    v3 = *(const uint4*)(ep4 + 1536);
  }
  DO_ROW(u0, u1, u2, u3, r0 + 2)
  DO_ROW(v0, v1, v2, v3, r0 + 3)

  // combine: waves 0-3 -> colA/colB, waves 4-7 -> colA2/colB2 (4 rounds)
  for (int ww = 0; ww < 4; ww++) {
    if (w == ww) {
      if (ww == 0) STORE8(colA, colB) else COMBINE8(colA, colB)
    } else if (w == ww + 4) {
      if (ww == 0) STORE8(colA2, colB2) else COMBINE8(colA2, colB2)
    }
    __syncthreads();
  }
  {  // epilogue: WAVE-COALESCED atomics; thread t owns columns {k*512+t}.
    int q = t & 7;
    const float* s1 = (q < 4) ? colA : colB;
    const float* s2 = (q < 4) ? colA2 : colB2;
    int qq = q & 3;
#pragma unroll
    for (int k = 0; k < 4; k++) {
      int j = k * 512 + t;
      int idx = (j >> 9) * 256 + ((j >> 3) & 63) * 4 + qq;
      atomicAdd(&cs_nxt[b * M + j], (s1[idx] + s2[idx]) * Ds[j]);
    }
  }
}

// ---------------------------------------------------------------------------
// Kernel 7: aw[i] = exp2(max_j fma(e,sL,C2L_j) + (KK - R_i)*log2e).
// ---------------------------------------------------------------------------
__global__ __launch_bounds__(256) void awmax_kernel(
    const ushort_t* __restrict__ e, const float* __restrict__ params,
    const float* __restrict__ cs_fin, const float* __restrict__ R,
    float* __restrict__ aw) {
  __shared__ __align__(16) float C2a[1024], C2b[1024];
  int t = threadIdx.x;
  int b = blockIdx.y, blk = blockIdx.x;
  const float* pr = params + b * 8;
  float sL = pr[0], c0L = pr[1], KK = pr[2], enk = pr[3];
  {
    float4 v0 = *(const float4*)(cs_fin + b * M + t * 8);
    float4 v1 = *(const float4*)(cs_fin + b * M + t * 8 + 4);
    float4 ca, cb;
    ca.x = c0L - flog2(v0.x + enk); ca.y = c0L - flog2(v0.y + enk);
    ca.z = c0L - flog2(v0.z + enk); ca.w = c0L - flog2(v0.w + enk);
    cb.x = c0L - flog2(v1.x + enk); cb.y = c0L - flog2(v1.y + enk);
    cb.z = c0L - flog2(v1.z + enk); cb.w = c0L - flog2(v1.w + enk);
    int it = t >> 6, ln = t & 63;
    *(float4*)&C2a[it * 256 + ln * 4] = ca;
    *(float4*)&C2b[it * 256 + ln * 4] = cb;
  }
  __syncthreads();

  int w = t >> 6, lane = t & 63;
  int ln4 = lane * 4;
  int r0 = blk * 16 + w * 4;
  const ushort_t* erow = e + (size_t)(b * N + r0) * M;
#pragma unroll
  for (int rr = 0; rr < 4; rr++) {
    float mx = -3.4e38f;
#pragma unroll
    for (int it = 0; it < 4; it++) {
      uint4 u = *(const uint4*)(erow + (size_t)rr * M + it * 512 + lane * 8);
      float4 ca = *(const float4*)&C2a[it * 256 + ln4];
      float4 cb = *(const float4*)&C2b[it * 256 + ln4];
      mx = fmaxf(mx, fmaf(blo(u.x), sL, ca.x));
      mx = fmaxf(mx, fmaf(bhi(u.x), sL, ca.y));
      mx = fmaxf(mx, fmaf(blo(u.y), sL, ca.z));
      mx = fmaxf(mx, fmaf(bhi(u.y), sL, ca.w));
      mx = fmaxf(mx, fmaf(blo(u.z), sL, cb.x));
      mx = fmaxf(mx, fmaf(bhi(u.z), sL, cb.y));
      mx = fmaxf(mx, fmaf(blo(u.w), sL, cb.z));
      mx = fmaxf(mx, fmaf(bhi(u.w), sL, cb.w));
    }
#pragma unroll
    for (int off = 32; off; off >>= 1) mx = fmaxf(mx, __shfl_xor(mx, off, 64));
    if (lane == 0) {
      float Rr = R[b * N + r0 + rr];
      aw[b * N + r0 + rr] = fexp2(mx + (KK - Rr) * LOG2E);
    }
  }
}

// ---------------------------------------------------------------------------
// Kernel 8: out[b,n,m] = aw[b,n] * aw[b,m], float4 stores.
// ---------------------------------------------------------------------------
__global__ __launch_bounds__(256) void outer_kernel(const float* __restrict__ aw,
                                                    float* __restrict__ out) {
  size_t idx = (size_t)blockIdx.x * 256 + threadIdx.x;
  int b = (int)(idx >> 20);
  size_t rem = idx & ((1u << 20) - 1);
  int n = (int)(rem >> 9);
  int m4 = (int)(rem & 511) << 2;
  float a = aw[b * N + n];
  float4 wv = *(const float4*)(aw + b * N + m4);
  float4 o = {a * wv.x, a * wv.y, a * wv.z, a * wv.w};
  *(float4*)(out + (idx << 2)) = o;
}

// ---------------------------------------------------------------------------
extern "C" void kernel_launch(void* const* d_in, const int* in_sizes, int n_in,
                              void* d_out, int out_size, void* d_ws, size_t ws_size,
                              hipStream_t stream) {
  const float* x = (const float*)d_in[0];
  const float* y = (const float*)d_in[1];
  const float* Wq = (const float*)d_in[2];
  const float* bq = (const float*)d_in[3];
  const float* in_w = (const float*)d_in[4];
  const float* in_b = (const float*)d_in[5];
  ushort_t* e = (ushort_t*)d_out;  // 33.5 MB bf16 scratch; overwritten by outer

  float* ws = (float*)d_ws;
  ushort_t* qwf = (ushort_t*)ws;     // 16384*64 bf16, fragment order
  float* norms = ws + 1048576;       // 16384
  float* R = norms + 16384;          // 8192
  float* csb0 = R + 8192;            // 8192
  float* csb1 = csb0 + 8192;         // 8192
  float* csb2 = csb1 + 8192;         // 8192
  float* aw = csb2 + 8192;           // 8192
  float* stats = aw + 8192;          // 32
  float* params = stats + 32;        // 32
  ushort_t* wqh = (ushort_t*)(params + 32);  // 64*512 bf16
  float* csb[3] = {csb0, csb1, csb2};

  wqconv_kernel<<<32, 256, 0, stream>>>(Wq, wqh);
  proj_kernel<<<256, 256, 0, stream>>>(x, y, wqh, bq, qwf, norms, stats);
  dist_kernel<<<dim3(16, 16, B), 256, 0, stream>>>(qwf, norms, e, stats);
  params_csinit_kernel<<<24, 256, 0, stream>>>(stats, in_w, in_b, params, csb0);

  for (int it = 0; it < ITERS; it++) {
    sink_pass<<<dim3(64, B), 512, 0, stream>>>(
        e, params, csb[it % 3], csb[(it + 1) % 3], csb[(it + 2) % 3], R);
  }
  awmax_kernel<<<dim3(128, B), 256, 0, stream>>>(e, params, csb[ITERS % 3], R, aw);
  outer_kernel<<<16384, 256, 0, stream>>>(aw, (float*)d_out);
}